// Round 12
// baseline (661.662 us; speedup 1.0000x reference)
//
#include <hip/hip_runtime.h>
#include <cstdint>

// AttCM R11: pass2 = skewed pipeline (PV shifted one iter: exp(i) || PV(i-1)
// in one barrier-free region -> VALU hides under MFMA; V-loads get full-body
// latency). Base-2 softmax: k scaled by log2e at QKV epilogue, exp2f
// everywhere (native v_exp_f32, drops one mul per exp). Else = R10.
// Shapes: B=8, C=256, HW=4096.

#define HW 4096
#define NB 8
#define LOG2E 1.44269504088896f

typedef __attribute__((ext_vector_type(8))) _Float16 half8;    // 8 fp16 = 4 VGPR
typedef __attribute__((ext_vector_type(4))) float f32x4;       // MFMA C/D

static __device__ __forceinline__ unsigned short f2h(float x) {
  _Float16 h = (_Float16)x;
  return __builtin_bit_cast(unsigned short, h);
}

// ---------------- 1x1 weights fp32 -> fp16, all six packed ----------------
__global__ __launch_bounds__(256) void wcvt6(
    const float* __restrict__ w1, const float* __restrict__ w2,
    const float* __restrict__ w3, const float* __restrict__ wq,
    const float* __restrict__ wk, const float* __restrict__ wv,
    unsigned short* __restrict__ dst) {
  int i = blockIdx.x * 256 + threadIdx.x;
  const float* src; int off;
  if      (i <  16384) { src = w1; off = 0; }
  else if (i <  24576) { src = w2; off = 16384; }
  else if (i <  57344) { src = w3; off = 24576; }
  else if (i < 122880) { src = wq; off = 57344; }
  else if (i < 188416) { src = wk; off = 122880; }
  else                 { src = wv; off = 188416; }
  dst[i] = f2h(src[i - off]);
}

// ---------------- conv weight reorder: OIHW fp32 -> [o][tap][c] fp16 --------
__global__ __launch_bounds__(256) void wreorder(
    const float* __restrict__ w, unsigned short* __restrict__ wA) {
  const int o = blockIdx.x;
  const int c = threadIdx.x;
  const float* wp = w + ((size_t)o * 256 + c) * 9;
#pragma unroll
  for (int tap = 0; tap < 9; tap++)
    wA[((size_t)o * 9 + tap) * 256 + c] = f2h(wp[tap]);
}

// ---------------- fp32 [b][c][p] -> fp16 transposed [b][p][c] ----------------
__global__ __launch_bounds__(256) void transpose_cvt_h(
    const float* __restrict__ in, unsigned short* __restrict__ outT) {
  __shared__ float Ts[64][65];
  const int b  = blockIdx.x;
  const int t0 = blockIdx.y * 64;
  const int c0 = blockIdx.z * 64;
  const int tid = threadIdx.x;
#pragma unroll
  for (int it = 0; it < 4; it++) {
    int id = tid + it * 256;
    int c = id >> 4, f4 = id & 15;
    float4 v = *(const float4*)(in + ((size_t)(b * 256 + c0 + c)) * HW + t0 + f4 * 4);
    Ts[c][f4 * 4 + 0] = v.x; Ts[c][f4 * 4 + 1] = v.y;
    Ts[c][f4 * 4 + 2] = v.z; Ts[c][f4 * 4 + 3] = v.w;
  }
  __syncthreads();
#pragma unroll
  for (int it = 0; it < 2; it++) {
    int id = tid + it * 256;
    int t = id >> 3, ch = id & 7;
    unsigned short h[8];
#pragma unroll
    for (int e = 0; e < 8; e++) h[e] = f2h(Ts[ch * 8 + e][t]);
    int4 pk;
    pk.x = (int)((unsigned)h[0] | ((unsigned)h[1] << 16));
    pk.y = (int)((unsigned)h[2] | ((unsigned)h[3] << 16));
    pk.z = (int)((unsigned)h[4] | ((unsigned)h[5] << 16));
    pk.w = (int)((unsigned)h[6] | ((unsigned)h[7] << 16));
    ((int4*)outT)[((size_t)b * HW + t0 + t) * 32 + (c0 >> 3) + ch] = pk;
  }
}

// ---------------- 1x1 conv: fp16 MFMA GEMM, fused layout epilogue ----------
__global__ __launch_bounds__(256) void gemm1x1_h(
    const unsigned short* __restrict__ Wh,   // fp16 [M][K]
    const float* __restrict__ bias,
    const unsigned short* __restrict__ Xt,   // fp16 [b][4096][K]
    unsigned short* __restrict__ outT,
    unsigned short* __restrict__ outN,
    int K, int M, int mode, int doRelu) {
  __shared__ int4 WsL[64 * 32];
  __shared__ int4 XsL[128 * 8];
  const int b  = blockIdx.x;
  const int p0 = blockIdx.y * 256;
  const int m0 = blockIdx.z * 64;
  const int tid = threadIdx.x;
  const int w = tid >> 6, l = tid & 63;
  const int l4 = l >> 4, l15 = l & 15;
  const int KG  = K >> 3;
  const int kgl = (K >= 256) ? 5 : (K >= 128) ? 4 : 3;
  const int4* Wh4 = (const int4*)Wh;
  const int4* Xt4 = (const int4*)Xt + (size_t)(b * 4096 + p0) * KG;
  for (int id = tid; id < 64 * KG; id += 256) {
    int row = id >> kgl, g = id & (KG - 1);
    WsL[row * KG + (g ^ (row & 7))] = Wh4[(size_t)(m0 + row) * KG + g];
  }
  f32x4 acc[4][4];
#pragma unroll
  for (int i = 0; i < 4; i++)
#pragma unroll
    for (int j = 0; j < 4; j++) acc[i][j] = {0.f, 0.f, 0.f, 0.f};
  const int NCC = K >> 5;
  for (int cc = 0; cc < NCC; cc++) {
    __syncthreads();
#pragma unroll
    for (int it = 0; it < 4; it++) {
      int id = tid + it * 256;
      int p = id >> 2, ch = id & 3;
      XsL[(p >> 1) * 8 + ((((p & 1) << 2) + ch) ^ ((p >> 1) & 7))] =
          Xt4[(size_t)p * KG + cc * 4 + ch];
    }
    __syncthreads();
    half8 a[4], bx[4];
#pragma unroll
    for (int mf = 0; mf < 4; mf++) {
      int m = mf * 16 + l15;
      a[mf] = ((const half8*)WsL)[m * KG + ((cc * 4 + l4) ^ (m & 7))];
    }
#pragma unroll
    for (int nf = 0; nf < 4; nf++) {
      int p = w * 64 + nf * 16 + l15;
      bx[nf] = ((const half8*)XsL)[(p >> 1) * 8 + ((((p & 1) << 2) + l4) ^ ((p >> 1) & 7))];
    }
#pragma unroll
    for (int mf = 0; mf < 4; mf++)
#pragma unroll
      for (int nf = 0; nf < 4; nf++)
        acc[mf][nf] = __builtin_amdgcn_mfma_f32_16x16x32_f16(a[mf], bx[nf], acc[mf][nf], 0, 0, 0);
  }
#pragma unroll
  for (int mf = 0; mf < 4; mf++) {
    const int mrow = m0 + mf * 16 + l4 * 4;
    const f32x4 bv = *(const f32x4*)(bias + mrow);
#pragma unroll
    for (int nf = 0; nf < 4; nf++) {
      const int p = p0 + w * 64 + nf * 16 + l15;
      float vr[4];
#pragma unroll
      for (int r = 0; r < 4; r++) {
        float v = acc[mf][nf][r] + bv[r];
        if (doRelu) v = fmaxf(v, 0.0f);
        vr[r] = v;
      }
      if (mode == 0) {
        unsigned long long pk = (unsigned long long)f2h(vr[0]) |
                                ((unsigned long long)f2h(vr[1]) << 16) |
                                ((unsigned long long)f2h(vr[2]) << 32) |
                                ((unsigned long long)f2h(vr[3]) << 48);
        *(unsigned long long*)(outT + ((size_t)b * 4096 + p) * M + mrow) = pk;
      } else {
#pragma unroll
        for (int r = 0; r < 4; r++)
          outN[((size_t)(b * M + mrow + r)) * 4096 + p] = f2h(vr[r]);
      }
    }
  }
}

// ---------------- fused QKV gemm: k scaled by log2e in epilogue -------------
__global__ __launch_bounds__(256) void gemm_qkv(
    const unsigned short* __restrict__ W768,  // fp16 [768][256] (wq|wk|wv)
    const float* __restrict__ bq, const float* __restrict__ bk,
    const float* __restrict__ bv_, const unsigned short* __restrict__ Xt,
    unsigned short* __restrict__ qT, unsigned short* __restrict__ kTo,
    unsigned short* __restrict__ vN) {
  __shared__ int4 WsL[64 * 32];
  __shared__ int4 XsL[128 * 8];
  const int b  = blockIdx.x;
  const int p0 = blockIdx.y * 256;
  const int z  = blockIdx.z;
  const int sel = z >> 2;
  const int m0 = (z & 3) * 64;
  const float* bias = (sel == 0) ? bq : (sel == 1) ? bk : bv_;
  const int tid = threadIdx.x;
  const int w = tid >> 6, l = tid & 63;
  const int l4 = l >> 4, l15 = l & 15;
  const int4* Wh4 = (const int4*)W768 + (size_t)sel * 256 * 32;
  const int4* Xt4 = (const int4*)Xt + (size_t)(b * 4096 + p0) * 32;
  for (int id = tid; id < 64 * 32; id += 256) {
    int row = id >> 5, g = id & 31;
    WsL[row * 32 + (g ^ (row & 7))] = Wh4[(size_t)(m0 + row) * 32 + g];
  }
  f32x4 acc[4][4];
#pragma unroll
  for (int i = 0; i < 4; i++)
#pragma unroll
    for (int j = 0; j < 4; j++) acc[i][j] = {0.f, 0.f, 0.f, 0.f};
  for (int cc = 0; cc < 8; cc++) {
    __syncthreads();
#pragma unroll
    for (int it = 0; it < 4; it++) {
      int id = tid + it * 256;
      int p = id >> 2, ch = id & 3;
      XsL[(p >> 1) * 8 + ((((p & 1) << 2) + ch) ^ ((p >> 1) & 7))] =
          Xt4[(size_t)p * 32 + cc * 4 + ch];
    }
    __syncthreads();
    half8 a[4], bx[4];
#pragma unroll
    for (int mf = 0; mf < 4; mf++) {
      int m = mf * 16 + l15;
      a[mf] = ((const half8*)WsL)[m * 32 + ((cc * 4 + l4) ^ (m & 7))];
    }
#pragma unroll
    for (int nf = 0; nf < 4; nf++) {
      int p = w * 64 + nf * 16 + l15;
      bx[nf] = ((const half8*)XsL)[(p >> 1) * 8 + ((((p & 1) << 2) + l4) ^ ((p >> 1) & 7))];
    }
#pragma unroll
    for (int mf = 0; mf < 4; mf++)
#pragma unroll
      for (int nf = 0; nf < 4; nf++)
        acc[mf][nf] = __builtin_amdgcn_mfma_f32_16x16x32_f16(a[mf], bx[nf], acc[mf][nf], 0, 0, 0);
  }
  unsigned short* outT = (sel == 0) ? qT : kTo;
#pragma unroll
  for (int mf = 0; mf < 4; mf++) {
    const int mrow = m0 + mf * 16 + l4 * 4;
    const f32x4 bvv = *(const f32x4*)(bias + mrow);
#pragma unroll
    for (int nf = 0; nf < 4; nf++) {
      const int p = p0 + w * 64 + nf * 16 + l15;
      float vr[4];
#pragma unroll
      for (int r = 0; r < 4; r++) {
        vr[r] = acc[mf][nf][r] + bvv[r];
        if (sel == 1) vr[r] *= LOG2E;     // base-2 softmax: S2 = S*log2e
      }
      if (sel < 2) {
        unsigned long long pk = (unsigned long long)f2h(vr[0]) |
                                ((unsigned long long)f2h(vr[1]) << 16) |
                                ((unsigned long long)f2h(vr[2]) << 32) |
                                ((unsigned long long)f2h(vr[3]) << 48);
        *(unsigned long long*)(outT + ((size_t)b * 4096 + p) * 256 + mrow) = pk;
      } else {
#pragma unroll
        for (int r = 0; r < 4; r++)
          vN[((size_t)(b * 256 + mrow + r)) * 4096 + p] = f2h(vr[r]);
      }
    }
  }
}

// ---------------- 3x3 conv, fp16 MFMA implicit GEMM (unchanged) ------------
__global__ __launch_bounds__(256, 2) void conv3x3_mfma(
    const unsigned short* __restrict__ inT,
    const unsigned short* __restrict__ wA,
    const float* __restrict__ bias,
    unsigned short* __restrict__ outT,
    float* __restrict__ outN,
    int mode) {
  __shared__ int4 wS[2304];
  __shared__ int4 inS[1584];
  const int b  = blockIdx.x;
  const int y0 = blockIdx.y * 4;
  const int o0 = blockIdx.z * 64;
  const int tid = threadIdx.x;
  const int w = tid >> 6, l = tid & 63;
  const int l4 = l >> 4, l15 = l & 15;
  const int4* inT4 = (const int4*)inT + (size_t)b * 4096 * 32;
  const int4* wA4  = (const int4*)wA;
  f32x4 acc[4][4];
#pragma unroll
  for (int i = 0; i < 4; i++)
#pragma unroll
    for (int j = 0; j < 4; j++) acc[i][j] = {0.f, 0.f, 0.f, 0.f};

  for (int c0 = 0; c0 < 256; c0 += 32) {
    __syncthreads();
#pragma unroll
    for (int it = 0; it < 9; it++) {
      int id = it * 256 + tid;
      int ch = id & 3;
      int r  = id >> 2;
      int tap = r % 9, ol = r / 9;
      int sbw = tap * 32 + (ol >> 1);
      int slot = (4 * (ol & 1) + ch) ^ (sbw & 7);
      wS[sbw * 8 + slot] = wA4[((size_t)(o0 + ol) * 9 + tap) * 32 + (c0 >> 3) + ch];
    }
#pragma unroll
    for (int it = 0; it < 6; it++) {
      int ch = tid & 3;
      int col = tid >> 2;
      int yimg = y0 + it - 1;
      int4 v = {0, 0, 0, 0};
      if (yimg >= 0 && yimg < 64)
        v = inT4[(size_t)(yimg * 64 + col) * 32 + (c0 >> 3) + ch];
      int cl = col + 1;
      int sb = it * 33 + (cl >> 1);
      int slot = (4 * (cl & 1) + ch) ^ (sb & 7);
      inS[sb * 8 + slot] = v;
    }
    if (tid < 48) {
      int row = tid >> 3;
      int cl = ((tid >> 2) & 1) ? 65 : 0;
      int ch = tid & 3;
      int sb = row * 33 + (cl >> 1);
      int slot = (4 * (cl & 1) + ch) ^ (sb & 7);
      inS[sb * 8 + slot] = {0, 0, 0, 0};
    }
    __syncthreads();
#pragma unroll
    for (int tap = 0; tap < 9; tap++) {
      const int dy = tap / 3, dx = tap % 3;
      half8 a[4], bf[4];
#pragma unroll
      for (int mf = 0; mf < 4; mf++) {
        int oc = mf * 16 + l15;
        int sbw = tap * 32 + (oc >> 1);
        a[mf] = ((const half8*)wS)[sbw * 8 + ((4 * (oc & 1) + l4) ^ (sbw & 7))];
      }
#pragma unroll
      for (int nf = 0; nf < 4; nf++) {
        int cl = nf * 16 + l15 + dx;
        int row = w + dy;
        int sb = row * 33 + (cl >> 1);
        bf[nf] = ((const half8*)inS)[sb * 8 + ((4 * (cl & 1) + l4) ^ (sb & 7))];
      }
#pragma unroll
      for (int mf = 0; mf < 4; mf++)
#pragma unroll
        for (int nf = 0; nf < 4; nf++)
          acc[mf][nf] = __builtin_amdgcn_mfma_f32_16x16x32_f16(a[mf], bf[nf], acc[mf][nf], 0, 0, 0);
    }
  }
  const int p_base = (y0 + w) * 64;
#pragma unroll
  for (int mf = 0; mf < 4; mf++) {
    const int ocb = o0 + mf * 16 + l4 * 4;
    const f32x4 bv = *(const f32x4*)(bias + ocb);
#pragma unroll
    for (int nf = 0; nf < 4; nf++) {
      const int p = p_base + nf * 16 + l15;
      if (mode == 0) {
        unsigned short h[4];
#pragma unroll
        for (int r = 0; r < 4; r++)
          h[r] = f2h(fmaxf(acc[mf][nf][r] + bv[r], 0.0f));
        unsigned long long pk = (unsigned long long)h[0] |
                                ((unsigned long long)h[1] << 16) |
                                ((unsigned long long)h[2] << 32) |
                                ((unsigned long long)h[3] << 48);
        *(unsigned long long*)(outT + ((size_t)b * 4096 + p) * 256 + ocb) = pk;
      } else {
#pragma unroll
        for (int r = 0; r < 4; r++)
          outN[((size_t)(b * 256 + ocb + r)) * HW + p] = acc[mf][nf][r] + bv[r];
      }
    }
  }
}

// ---------------- attention pass 1a (R10 structure, exp2) -------------------
__global__ __launch_bounds__(256) void attn_rowstats_part(
    const unsigned short* __restrict__ kT, const unsigned short* __restrict__ qT,
    float* __restrict__ Mp, float* __restrict__ Zp) {
  __shared__ int4 qs4[64][32];   // 32KB [t][c-granule], swizzled
  const int b  = blockIdx.x;
  const int r0 = blockIdx.y * 64;
  const int q  = blockIdx.z;
  const int tid = threadIdx.x;
  const int w = tid >> 6, l = tid & 63;
  const int l4 = l >> 4, l15 = l & 15;
  const int4* qT4 = (const int4*)qT + (size_t)b * HW * 32;
  const half8* kT8 = (const half8*)kT + ((size_t)b * HW + r0) * 32;
  half8 afr[4][8];               // all 64 rows: [mfl][g]
#pragma unroll
  for (int mfl = 0; mfl < 4; mfl++)
#pragma unroll
    for (int g = 0; g < 8; g++)
      afr[mfl][g] = kT8[(size_t)(mfl * 16 + l15) * 32 + g * 4 + l4];
  float m[4][4], z[4][4];        // [mfl][reg]
#pragma unroll
  for (int i = 0; i < 4; i++)
#pragma unroll
    for (int j = 0; j < 4; j++) { m[i][j] = -1e30f; z[i][j] = 0.0f; }
  for (int t0 = q * 1024; t0 < q * 1024 + 1024; t0 += 64) {
    __syncthreads();
#pragma unroll
    for (int it = 0; it < 8; it++) {
      int id = tid + it * 256;
      int row = id >> 5, ch = id & 31;
      qs4[row][ch ^ (row & 7)] = qT4[(size_t)(t0 + row) * 32 + ch];
    }
    __syncthreads();
    f32x4 acc[4] = {{0.f,0.f,0.f,0.f},{0.f,0.f,0.f,0.f},
                    {0.f,0.f,0.f,0.f},{0.f,0.f,0.f,0.f}};
    const int t = w * 16 + l15;  // this wave's t-slice
#pragma unroll
    for (int g = 0; g < 8; g++) {
      half8 bq = ((const half8*)qs4)[t * 32 + ((g * 4 + l4) ^ (t & 7))];
#pragma unroll
      for (int mfl = 0; mfl < 4; mfl++)
        acc[mfl] = __builtin_amdgcn_mfma_f32_16x16x32_f16(afr[mfl][g], bq, acc[mfl], 0, 0, 0);
    }
#pragma unroll
    for (int mfl = 0; mfl < 4; mfl++)
#pragma unroll
      for (int r = 0; r < 4; r++) {
        float sv = acc[mfl][r];
        if (sv > m[mfl][r]) { z[mfl][r] *= exp2f(m[mfl][r] - sv); m[mfl][r] = sv; }
        z[mfl][r] += exp2f(sv - m[mfl][r]);
      }
  }
#pragma unroll
  for (int mfl = 0; mfl < 4; mfl++)
#pragma unroll
    for (int r = 0; r < 4; r++) {
      for (int off = 1; off < 16; off <<= 1) {
        float mo = __shfl_xor(m[mfl][r], off, 16);
        float zo = __shfl_xor(z[mfl][r], off, 16);
        float mn = fmaxf(m[mfl][r], mo);
        z[mfl][r] = z[mfl][r] * exp2f(m[mfl][r] - mn) + zo * exp2f(mo - mn);
        m[mfl][r] = mn;
      }
    }
  if (l15 == 0) {
#pragma unroll
    for (int mfl = 0; mfl < 4; mfl++)
#pragma unroll
      for (int r = 0; r < 4; r++) {
        int rr = r0 + mfl * 16 + l4 * 4 + r;
        Mp[((size_t)b * HW + rr) * 16 + q * 4 + w] = m[mfl][r];
        Zp[((size_t)b * HW + rr) * 16 + q * 4 + w] = z[mfl][r];
      }
  }
}

// ---------------- attention pass 1b: merge 16 partials (exp2) ---------------
__global__ __launch_bounds__(256) void reduce_mz(
    const float* __restrict__ Mp, const float* __restrict__ Zp,
    float* __restrict__ Mrow, float* __restrict__ Zrow) {
  int i = blockIdx.x * 256 + threadIdx.x;      // 0 .. 8*4096-1
  float mq[16], zq[16];
#pragma unroll
  for (int j = 0; j < 4; j++) {
    float4 mv = *(const float4*)(Mp + (size_t)i * 16 + j * 4);
    float4 zv = *(const float4*)(Zp + (size_t)i * 16 + j * 4);
    mq[j*4+0] = mv.x; mq[j*4+1] = mv.y; mq[j*4+2] = mv.z; mq[j*4+3] = mv.w;
    zq[j*4+0] = zv.x; zq[j*4+1] = zv.y; zq[j*4+2] = zv.z; zq[j*4+3] = zv.w;
  }
  float M = mq[0];
#pragma unroll
  for (int j = 1; j < 16; j++) M = fmaxf(M, mq[j]);
  float Z = 0.0f;
#pragma unroll
  for (int j = 0; j < 16; j++) Z += zq[j] * exp2f(mq[j] - M);
  Mrow[i] = M;
  Zrow[i] = 1.0f / Z;
}

// ---------------- attention pass 2: skewed pipeline -------------------------
// body(I): Kload+S-MFMA(I); Vload(I)->AVRC; exp2(I)->psb[I&1];
//          PV(I-1) from psb[(I-1)&1]+AVRP (interleaves with exp); barrier.
// Parity audit: psb[I&1] write vs PV(I-1) read psb[(I-1)&1] = other buffer;
// exp(I+1) overwrite of psb[(I-1)&1] is after barrier(I) which follows all
// waves' PV(I-1). avr sets ping-pong via static names (2x-unrolled).
#define P2B(I, AVRC, AVRP, DOPV)                                               \
  {                                                                            \
    const int r0 = (I) * 128;                                                  \
    unsigned long long* pw = (unsigned long long*)&ps4[(I) & 1][0][0];         \
    const half8* pr = (const half8*)&ps4[1 - ((I) & 1)][0][0];                 \
    half8 ak0[8], ak1[8];                                                      \
    _Pragma("unroll")                                                          \
    for (int g = 0; g < 8; g++) {                                              \
      ak0[g] = kT8[(size_t)(r0 + w * 32 + l15) * 32 + g * 4 + l4];             \
      ak1[g] = kT8[(size_t)(r0 + w * 32 + 16 + l15) * 32 + g * 4 + l4];        \
    }                                                                          \
    f32x4 acc_s[2][4];                                                         \
    _Pragma("unroll")                                                          \
    for (int i = 0; i < 2; i++)                                                \
      _Pragma("unroll")                                                        \
      for (int j = 0; j < 4; j++) acc_s[i][j] = {0.f, 0.f, 0.f, 0.f};          \
    _Pragma("unroll")                                                          \
    for (int g = 0; g < 8; g++) {                                              \
      half8 bq[4];                                                             \
      _Pragma("unroll")                                                        \
      for (int nf = 0; nf < 4; nf++) {                                         \
        int t = nf * 16 + l15;                                                 \
        bq[nf] = ((const half8*)qs4)[t * 32 + ((g * 4 + l4) ^ (t & 7))];       \
      }                                                                        \
      _Pragma("unroll")                                                        \
      for (int nf = 0; nf < 4; nf++) {                                         \
        acc_s[0][nf] = __builtin_amdgcn_mfma_f32_16x16x32_f16(ak0[g], bq[nf], acc_s[0][nf], 0, 0, 0); \
        acc_s[1][nf] = __builtin_amdgcn_mfma_f32_16x16x32_f16(ak1[g], bq[nf], acc_s[1][nf], 0, 0, 0); \
      }                                                                        \
    }                                                                          \
    _Pragma("unroll")                                                          \
    for (int cc4 = 0; cc4 < 4; cc4++) {                                        \
      const int c = cc4 * 64 + w * 16 + l15;                                   \
      _Pragma("unroll")                                                        \
      for (int ks = 0; ks < 4; ks++)                                           \
        AVRC[cc4][ks] = vB8[(size_t)c * 512 + (r0 >> 3) + ks * 4 + l4];        \
    }                                                                          \
    _Pragma("unroll")                                                          \
    for (int mfl = 0; mfl < 2; mfl++) {                                        \
      int rbase = r0 + w * 32 + mfl * 16 + l4 * 4;                             \
      f32x4 Mv = *(const f32x4*)(Mb + rbase);                                  \
      f32x4 Zv = *(const f32x4*)(Zb + rbase);                                  \
      int slot = w * 8 + mfl * 4 + l4;                                         \
      _Pragma("unroll")                                                        \
      for (int nf = 0; nf < 4; nf++) {                                         \
        int t = nf * 16 + l15;                                                 \
        unsigned lo = (unsigned)f2h(exp2f(acc_s[mfl][nf][0] - Mv[0]) * Zv[0])  \
                    | ((unsigned)f2h(exp2f(acc_s[mfl][nf][1] - Mv[1]) * Zv[1]) << 16); \
        unsigned hi = (unsigned)f2h(exp2f(acc_s[mfl][nf][2] - Mv[2]) * Zv[2])  \
                    | ((unsigned)f2h(exp2f(acc_s[mfl][nf][3] - Mv[3]) * Zv[3]) << 16); \
        int ch = slot >> 1;                                                    \
        int fslot = ((ch ^ (t & 7)) << 1) | (slot & 1);                        \
        pw[(size_t)t * 32 + fslot] =                                           \
            ((unsigned long long)hi << 32) | (unsigned long long)lo;           \
      }                                                                        \
    }                                                                          \
    if (DOPV) {                                                                \
      _Pragma("unroll")                                                        \
      for (int ks = 0; ks < 4; ks++) {                                         \
        _Pragma("unroll")                                                      \
        for (int nf = 0; nf < 4; nf++) {                                       \
          int t = nf * 16 + l15;                                               \
          half8 bp = pr[t * 16 + ((ks * 4 + l4) ^ (t & 7))];                   \
          _Pragma("unroll")                                                    \
          for (int cc4 = 0; cc4 < 4; cc4++)                                    \
            acc_o[cc4][nf] = __builtin_amdgcn_mfma_f32_16x16x32_f16(AVRP[cc4][ks], bp, acc_o[cc4][nf], 0, 0, 0); \
        }                                                                      \
      }                                                                        \
    }                                                                          \
    __syncthreads();                                                           \
  }

__global__ __launch_bounds__(256, 2) void attn_pass2(
    const unsigned short* __restrict__ kT, const unsigned short* __restrict__ qT,
    const unsigned short* __restrict__ vB, const float* __restrict__ Mrow,
    const float* __restrict__ Zrow, const float* __restrict__ alphap,
    const float* __restrict__ betap, float* __restrict__ out) {
  __shared__ int4 qs4[64][32];      // 32KB Q [t][c-granule], swizzled
  __shared__ int4 ps4[2][64][16];   // 2x16KB P [t][r-granule], swizzled
  const int b  = blockIdx.x;
  const int t0 = blockIdx.y * 64;
  const int tid = threadIdx.x;
  const int w = tid >> 6, l = tid & 63;
  const int l4 = l >> 4, l15 = l & 15;
  const int4*  qT4 = (const int4*)qT + ((size_t)b * HW + t0) * 32;
  const half8* kT8 = (const half8*)kT + (size_t)b * HW * 32;
  const half8* vB8 = (const half8*)vB + (size_t)b * 256 * 512;
  const float* Mb = Mrow + (size_t)b * HW;
  const float* Zb = Zrow + (size_t)b * HW;
#pragma unroll
  for (int it = 0; it < 8; it++) {
    int id = tid + it * 256;
    int row = id >> 5, ch = id & 31;
    qs4[row][ch ^ (row & 7)] = qT4[(size_t)row * 32 + ch];
  }
  f32x4 acc_o[4][4];
#pragma unroll
  for (int i = 0; i < 4; i++)
#pragma unroll
    for (int j = 0; j < 4; j++) acc_o[i][j] = {0.f, 0.f, 0.f, 0.f};
  half8 avrA[4][4], avrB[4][4];
  __syncthreads();                  // Q staged

  P2B(0, avrA, avrB, 0)             // S/exp/Vload only, no PV(-1)
#pragma unroll 1
  for (int it2 = 0; it2 < 15; it2++) {
    P2B(2 * it2 + 1, avrB, avrA, 1)
    P2B(2 * it2 + 2, avrA, avrB, 1)
  }
  P2B(31, avrB, avrA, 1)            // PV(30) inside; psb[1], avrB hold iter 31

  // final PV(31): psb[31&1]=ps4[1], V in avrB (barrier at end of P2B(31) done)
#pragma unroll
  for (int ks = 0; ks < 4; ks++) {
#pragma unroll
    for (int nf = 0; nf < 4; nf++) {
      int t = nf * 16 + l15;
      half8 bp = ((const half8*)&ps4[1][0][0])[t * 16 + ((ks * 4 + l4) ^ (t & 7))];
#pragma unroll
      for (int cc4 = 0; cc4 < 4; cc4++)
        acc_o[cc4][nf] = __builtin_amdgcn_mfma_f32_16x16x32_f16(avrB[cc4][ks], bp, acc_o[cc4][nf], 0, 0, 0);
    }
  }

  const float alpha = alphap[0], beta = betap[0];
#pragma unroll
  for (int cc4 = 0; cc4 < 4; cc4++) {
    int cbase = cc4 * 64 + w * 16 + l4 * 4;
#pragma unroll
    for (int nf = 0; nf < 4; nf++) {
      int t = t0 + nf * 16 + l15;
#pragma unroll
      for (int r = 0; r < 4; r++) {
        size_t idx = ((size_t)(b * 256 + cbase + r)) * HW + t;
        out[idx] = alpha * out[idx] + beta * acc_o[cc4][nf][r];
      }
    }
  }
}

extern "C" void kernel_launch(void* const* d_in, const int* in_sizes, int n_in,
                              void* d_out, int out_size, void* d_ws, size_t ws_size,
                              hipStream_t stream) {
  (void)in_sizes; (void)n_in; (void)out_size; (void)ws_size;
  const float* x   = (const float*)d_in[0];
  const float* w1  = (const float*)d_in[1];
  const float* b1  = (const float*)d_in[2];
  const float* w2  = (const float*)d_in[3];
  const float* b2  = (const float*)d_in[4];
  const float* w3  = (const float*)d_in[5];
  const float* b3  = (const float*)d_in[6];
  const float* wb1 = (const float*)d_in[7];
  const float* bb1 = (const float*)d_in[8];
  const float* wb2 = (const float*)d_in[9];
  const float* bb2 = (const float*)d_in[10];
  const float* wq  = (const float*)d_in[11];
  const float* bq  = (const float*)d_in[12];
  const float* wk  = (const float*)d_in[13];
  const float* bk  = (const float*)d_in[14];
  const float* wv  = (const float*)d_in[15];
  const float* bv  = (const float*)d_in[16];
  const float* alpha = (const float*)d_in[17];
  const float* beta  = (const float*)d_in[18];
  float* out = (float*)d_out;

  const size_t SZH = (size_t)NB * 4096 * 256;   // 8,388,608 halves = 16MB
  unsigned short* wsh = (unsigned short*)d_ws;
  unsigned short* xh  = wsh;
  unsigned short* xfT = wsh + SZH;
  unsigned short* qT  = wsh + 2 * SZH;
  unsigned short* kT  = wsh + 3 * SZH;
  unsigned short* vN  = wsh + 4 * SZH;
  unsigned short* y1T = wsh + 5 * SZH;
  unsigned short* y2T = y1T + SZH / 4;
  unsigned short* t1T = wsh + 5 * SZH;
  float* Mrow = (float*)(wsh + 6 * SZH);
  float* Zrow = Mrow + (size_t)NB * HW;
  float* Mp   = Zrow + (size_t)NB * HW;         // [B*HW*16] partials
  float* Zp   = Mp + (size_t)NB * HW * 16;
  unsigned short* wh   = (unsigned short*)(Zp + (size_t)NB * HW * 16);
  unsigned short* w1h  = wh;
  unsigned short* w2h  = wh + 16384;
  unsigned short* w3h  = wh + 24576;
  unsigned short* wqh  = wh + 57344;            // [768][256] contiguous q|k|v
  unsigned short* wA1h = wh + 253952;
  unsigned short* wA2h = wA1h + (size_t)256 * 9 * 256;

  wcvt6<<<992, 256, 0, stream>>>(w1, w2, w3, wq, wk, wv, wh);
  wreorder<<<256, 256, 0, stream>>>(wb1, wA1h);
  wreorder<<<256, 256, 0, stream>>>(wb2, wA2h);
  transpose_cvt_h<<<dim3(8, 64, 4), 256, 0, stream>>>(x, xh);
  gemm1x1_h<<<dim3(8, 16, 1), 256, 0, stream>>>(w1h, b1, xh,  y1T, nullptr, 256,  64, 0, 1);
  gemm1x1_h<<<dim3(8, 16, 2), 256, 0, stream>>>(w2h, b2, y1T, y2T, nullptr,  64, 128, 0, 1);
  gemm1x1_h<<<dim3(8, 16, 4), 256, 0, stream>>>(w3h, b3, y2T, xfT, nullptr, 128, 256, 0, 1);
  gemm_qkv<<<dim3(8, 16, 12), 256, 0, stream>>>(wqh, bq, bk, bv, xfT, qT, kT, vN);
  conv3x3_mfma<<<dim3(8, 16, 4), 256, 0, stream>>>(xfT, wA1h, bb1, t1T, nullptr, 0);
  conv3x3_mfma<<<dim3(8, 16, 4), 256, 0, stream>>>(t1T, wA2h, bb2, nullptr, out, 1);
  attn_rowstats_part<<<dim3(8, 64, 4), 256, 0, stream>>>(kT, qT, Mp, Zp);
  reduce_mz<<<128, 256, 0, stream>>>(Mp, Zp, Mrow, Zrow);
  attn_pass2<<<dim3(8, 64), 256, 0, stream>>>(kT, qT, vN, Mrow, Zrow,
                                              alpha, beta, out);
}

// Round 13
// 574.960 us; speedup vs baseline: 1.1508x; 1.1508x over previous
//
#include <hip/hip_runtime.h>
#include <cstdint>

// AttCM R12: revert R11's exp2/LOG2E regression (back to __expf, R10 front).
// pass2 = producer/consumer wave specialization: waves{0,1}=S+exp+psb-write,
// waves{2,3}=V-load+PV (one iter behind); role flipped by blockIdx parity so
// each SIMD hosts producer+consumer -> MFMA||VALU||VMEM overlap (m114).
// Seven same-phase variants all hit 275-285us = pipe-SUM; this breaks the sum.
// Shapes: B=8, C=256, HW=4096.

#define HW 4096
#define NB 8

typedef __attribute__((ext_vector_type(8))) _Float16 half8;    // 8 fp16 = 4 VGPR
typedef __attribute__((ext_vector_type(4))) float f32x4;       // MFMA C/D

static __device__ __forceinline__ unsigned short f2h(float x) {
  _Float16 h = (_Float16)x;
  return __builtin_bit_cast(unsigned short, h);
}

// ---------------- 1x1 weights fp32 -> fp16, all six packed ----------------
__global__ __launch_bounds__(256) void wcvt6(
    const float* __restrict__ w1, const float* __restrict__ w2,
    const float* __restrict__ w3, const float* __restrict__ wq,
    const float* __restrict__ wk, const float* __restrict__ wv,
    unsigned short* __restrict__ dst) {
  int i = blockIdx.x * 256 + threadIdx.x;
  const float* src; int off;
  if      (i <  16384) { src = w1; off = 0; }
  else if (i <  24576) { src = w2; off = 16384; }
  else if (i <  57344) { src = w3; off = 24576; }
  else if (i < 122880) { src = wq; off = 57344; }
  else if (i < 188416) { src = wk; off = 122880; }
  else                 { src = wv; off = 188416; }
  dst[i] = f2h(src[i - off]);
}

// ---------------- conv weight reorder: OIHW fp32 -> [o][tap][c] fp16 --------
__global__ __launch_bounds__(256) void wreorder(
    const float* __restrict__ w, unsigned short* __restrict__ wA) {
  const int o = blockIdx.x;
  const int c = threadIdx.x;
  const float* wp = w + ((size_t)o * 256 + c) * 9;
#pragma unroll
  for (int tap = 0; tap < 9; tap++)
    wA[((size_t)o * 9 + tap) * 256 + c] = f2h(wp[tap]);
}

// ---------------- fp32 [b][c][p] -> fp16 transposed [b][p][c] ----------------
__global__ __launch_bounds__(256) void transpose_cvt_h(
    const float* __restrict__ in, unsigned short* __restrict__ outT) {
  __shared__ float Ts[64][65];
  const int b  = blockIdx.x;
  const int t0 = blockIdx.y * 64;
  const int c0 = blockIdx.z * 64;
  const int tid = threadIdx.x;
#pragma unroll
  for (int it = 0; it < 4; it++) {
    int id = tid + it * 256;
    int c = id >> 4, f4 = id & 15;
    float4 v = *(const float4*)(in + ((size_t)(b * 256 + c0 + c)) * HW + t0 + f4 * 4);
    Ts[c][f4 * 4 + 0] = v.x; Ts[c][f4 * 4 + 1] = v.y;
    Ts[c][f4 * 4 + 2] = v.z; Ts[c][f4 * 4 + 3] = v.w;
  }
  __syncthreads();
#pragma unroll
  for (int it = 0; it < 2; it++) {
    int id = tid + it * 256;
    int t = id >> 3, ch = id & 7;
    unsigned short h[8];
#pragma unroll
    for (int e = 0; e < 8; e++) h[e] = f2h(Ts[ch * 8 + e][t]);
    int4 pk;
    pk.x = (int)((unsigned)h[0] | ((unsigned)h[1] << 16));
    pk.y = (int)((unsigned)h[2] | ((unsigned)h[3] << 16));
    pk.z = (int)((unsigned)h[4] | ((unsigned)h[5] << 16));
    pk.w = (int)((unsigned)h[6] | ((unsigned)h[7] << 16));
    ((int4*)outT)[((size_t)b * HW + t0 + t) * 32 + (c0 >> 3) + ch] = pk;
  }
}

// ---------------- 1x1 conv: fp16 MFMA GEMM, fused layout epilogue ----------
__global__ __launch_bounds__(256) void gemm1x1_h(
    const unsigned short* __restrict__ Wh,   // fp16 [M][K]
    const float* __restrict__ bias,
    const unsigned short* __restrict__ Xt,   // fp16 [b][4096][K]
    unsigned short* __restrict__ outT,
    unsigned short* __restrict__ outN,
    int K, int M, int mode, int doRelu) {
  __shared__ int4 WsL[64 * 32];
  __shared__ int4 XsL[128 * 8];
  const int b  = blockIdx.x;
  const int p0 = blockIdx.y * 256;
  const int m0 = blockIdx.z * 64;
  const int tid = threadIdx.x;
  const int w = tid >> 6, l = tid & 63;
  const int l4 = l >> 4, l15 = l & 15;
  const int KG  = K >> 3;
  const int kgl = (K >= 256) ? 5 : (K >= 128) ? 4 : 3;
  const int4* Wh4 = (const int4*)Wh;
  const int4* Xt4 = (const int4*)Xt + (size_t)(b * 4096 + p0) * KG;
  for (int id = tid; id < 64 * KG; id += 256) {
    int row = id >> kgl, g = id & (KG - 1);
    WsL[row * KG + (g ^ (row & 7))] = Wh4[(size_t)(m0 + row) * KG + g];
  }
  f32x4 acc[4][4];
#pragma unroll
  for (int i = 0; i < 4; i++)
#pragma unroll
    for (int j = 0; j < 4; j++) acc[i][j] = {0.f, 0.f, 0.f, 0.f};
  const int NCC = K >> 5;
  for (int cc = 0; cc < NCC; cc++) {
    __syncthreads();
#pragma unroll
    for (int it = 0; it < 4; it++) {
      int id = tid + it * 256;
      int p = id >> 2, ch = id & 3;
      XsL[(p >> 1) * 8 + ((((p & 1) << 2) + ch) ^ ((p >> 1) & 7))] =
          Xt4[(size_t)p * KG + cc * 4 + ch];
    }
    __syncthreads();
    half8 a[4], bx[4];
#pragma unroll
    for (int mf = 0; mf < 4; mf++) {
      int m = mf * 16 + l15;
      a[mf] = ((const half8*)WsL)[m * KG + ((cc * 4 + l4) ^ (m & 7))];
    }
#pragma unroll
    for (int nf = 0; nf < 4; nf++) {
      int p = w * 64 + nf * 16 + l15;
      bx[nf] = ((const half8*)XsL)[(p >> 1) * 8 + ((((p & 1) << 2) + l4) ^ ((p >> 1) & 7))];
    }
#pragma unroll
    for (int mf = 0; mf < 4; mf++)
#pragma unroll
      for (int nf = 0; nf < 4; nf++)
        acc[mf][nf] = __builtin_amdgcn_mfma_f32_16x16x32_f16(a[mf], bx[nf], acc[mf][nf], 0, 0, 0);
  }
#pragma unroll
  for (int mf = 0; mf < 4; mf++) {
    const int mrow = m0 + mf * 16 + l4 * 4;
    const f32x4 bv = *(const f32x4*)(bias + mrow);
#pragma unroll
    for (int nf = 0; nf < 4; nf++) {
      const int p = p0 + w * 64 + nf * 16 + l15;
      float vr[4];
#pragma unroll
      for (int r = 0; r < 4; r++) {
        float v = acc[mf][nf][r] + bv[r];
        if (doRelu) v = fmaxf(v, 0.0f);
        vr[r] = v;
      }
      if (mode == 0) {
        unsigned long long pk = (unsigned long long)f2h(vr[0]) |
                                ((unsigned long long)f2h(vr[1]) << 16) |
                                ((unsigned long long)f2h(vr[2]) << 32) |
                                ((unsigned long long)f2h(vr[3]) << 48);
        *(unsigned long long*)(outT + ((size_t)b * 4096 + p) * M + mrow) = pk;
      } else {
#pragma unroll
        for (int r = 0; r < 4; r++)
          outN[((size_t)(b * M + mrow + r)) * 4096 + p] = f2h(vr[r]);
      }
    }
  }
}

// ---------------- fused QKV gemm (R10, no scaling) --------------------------
__global__ __launch_bounds__(256) void gemm_qkv(
    const unsigned short* __restrict__ W768,  // fp16 [768][256] (wq|wk|wv)
    const float* __restrict__ bq, const float* __restrict__ bk,
    const float* __restrict__ bv_, const unsigned short* __restrict__ Xt,
    unsigned short* __restrict__ qT, unsigned short* __restrict__ kTo,
    unsigned short* __restrict__ vN) {
  __shared__ int4 WsL[64 * 32];
  __shared__ int4 XsL[128 * 8];
  const int b  = blockIdx.x;
  const int p0 = blockIdx.y * 256;
  const int z  = blockIdx.z;
  const int sel = z >> 2;
  const int m0 = (z & 3) * 64;
  const float* bias = (sel == 0) ? bq : (sel == 1) ? bk : bv_;
  const int tid = threadIdx.x;
  const int w = tid >> 6, l = tid & 63;
  const int l4 = l >> 4, l15 = l & 15;
  const int4* Wh4 = (const int4*)W768 + (size_t)sel * 256 * 32;
  const int4* Xt4 = (const int4*)Xt + (size_t)(b * 4096 + p0) * 32;
  for (int id = tid; id < 64 * 32; id += 256) {
    int row = id >> 5, g = id & 31;
    WsL[row * 32 + (g ^ (row & 7))] = Wh4[(size_t)(m0 + row) * 32 + g];
  }
  f32x4 acc[4][4];
#pragma unroll
  for (int i = 0; i < 4; i++)
#pragma unroll
    for (int j = 0; j < 4; j++) acc[i][j] = {0.f, 0.f, 0.f, 0.f};
  for (int cc = 0; cc < 8; cc++) {
    __syncthreads();
#pragma unroll
    for (int it = 0; it < 4; it++) {
      int id = tid + it * 256;
      int p = id >> 2, ch = id & 3;
      XsL[(p >> 1) * 8 + ((((p & 1) << 2) + ch) ^ ((p >> 1) & 7))] =
          Xt4[(size_t)p * 32 + cc * 4 + ch];
    }
    __syncthreads();
    half8 a[4], bx[4];
#pragma unroll
    for (int mf = 0; mf < 4; mf++) {
      int m = mf * 16 + l15;
      a[mf] = ((const half8*)WsL)[m * 32 + ((cc * 4 + l4) ^ (m & 7))];
    }
#pragma unroll
    for (int nf = 0; nf < 4; nf++) {
      int p = w * 64 + nf * 16 + l15;
      bx[nf] = ((const half8*)XsL)[(p >> 1) * 8 + ((((p & 1) << 2) + l4) ^ ((p >> 1) & 7))];
    }
#pragma unroll
    for (int mf = 0; mf < 4; mf++)
#pragma unroll
      for (int nf = 0; nf < 4; nf++)
        acc[mf][nf] = __builtin_amdgcn_mfma_f32_16x16x32_f16(a[mf], bx[nf], acc[mf][nf], 0, 0, 0);
  }
  unsigned short* outT = (sel == 0) ? qT : kTo;
#pragma unroll
  for (int mf = 0; mf < 4; mf++) {
    const int mrow = m0 + mf * 16 + l4 * 4;
    const f32x4 bvv = *(const f32x4*)(bias + mrow);
#pragma unroll
    for (int nf = 0; nf < 4; nf++) {
      const int p = p0 + w * 64 + nf * 16 + l15;
      float vr[4];
#pragma unroll
      for (int r = 0; r < 4; r++) vr[r] = acc[mf][nf][r] + bvv[r];
      if (sel < 2) {
        unsigned long long pk = (unsigned long long)f2h(vr[0]) |
                                ((unsigned long long)f2h(vr[1]) << 16) |
                                ((unsigned long long)f2h(vr[2]) << 32) |
                                ((unsigned long long)f2h(vr[3]) << 48);
        *(unsigned long long*)(outT + ((size_t)b * 4096 + p) * 256 + mrow) = pk;
      } else {
#pragma unroll
        for (int r = 0; r < 4; r++)
          vN[((size_t)(b * 256 + mrow + r)) * 4096 + p] = f2h(vr[r]);
      }
    }
  }
}

// ---------------- 3x3 conv, fp16 MFMA implicit GEMM (unchanged) ------------
__global__ __launch_bounds__(256, 2) void conv3x3_mfma(
    const unsigned short* __restrict__ inT,
    const unsigned short* __restrict__ wA,
    const float* __restrict__ bias,
    unsigned short* __restrict__ outT,
    float* __restrict__ outN,
    int mode) {
  __shared__ int4 wS[2304];
  __shared__ int4 inS[1584];
  const int b  = blockIdx.x;
  const int y0 = blockIdx.y * 4;
  const int o0 = blockIdx.z * 64;
  const int tid = threadIdx.x;
  const int w = tid >> 6, l = tid & 63;
  const int l4 = l >> 4, l15 = l & 15;
  const int4* inT4 = (const int4*)inT + (size_t)b * 4096 * 32;
  const int4* wA4  = (const int4*)wA;
  f32x4 acc[4][4];
#pragma unroll
  for (int i = 0; i < 4; i++)
#pragma unroll
    for (int j = 0; j < 4; j++) acc[i][j] = {0.f, 0.f, 0.f, 0.f};

  for (int c0 = 0; c0 < 256; c0 += 32) {
    __syncthreads();
#pragma unroll
    for (int it = 0; it < 9; it++) {
      int id = it * 256 + tid;
      int ch = id & 3;
      int r  = id >> 2;
      int tap = r % 9, ol = r / 9;
      int sbw = tap * 32 + (ol >> 1);
      int slot = (4 * (ol & 1) + ch) ^ (sbw & 7);
      wS[sbw * 8 + slot] = wA4[((size_t)(o0 + ol) * 9 + tap) * 32 + (c0 >> 3) + ch];
    }
#pragma unroll
    for (int it = 0; it < 6; it++) {
      int ch = tid & 3;
      int col = tid >> 2;
      int yimg = y0 + it - 1;
      int4 v = {0, 0, 0, 0};
      if (yimg >= 0 && yimg < 64)
        v = inT4[(size_t)(yimg * 64 + col) * 32 + (c0 >> 3) + ch];
      int cl = col + 1;
      int sb = it * 33 + (cl >> 1);
      int slot = (4 * (cl & 1) + ch) ^ (sb & 7);
      inS[sb * 8 + slot] = v;
    }
    if (tid < 48) {
      int row = tid >> 3;
      int cl = ((tid >> 2) & 1) ? 65 : 0;
      int ch = tid & 3;
      int sb = row * 33 + (cl >> 1);
      int slot = (4 * (cl & 1) + ch) ^ (sb & 7);
      inS[sb * 8 + slot] = {0, 0, 0, 0};
    }
    __syncthreads();
#pragma unroll
    for (int tap = 0; tap < 9; tap++) {
      const int dy = tap / 3, dx = tap % 3;
      half8 a[4], bf[4];
#pragma unroll
      for (int mf = 0; mf < 4; mf++) {
        int oc = mf * 16 + l15;
        int sbw = tap * 32 + (oc >> 1);
        a[mf] = ((const half8*)wS)[sbw * 8 + ((4 * (oc & 1) + l4) ^ (sbw & 7))];
      }
#pragma unroll
      for (int nf = 0; nf < 4; nf++) {
        int cl = nf * 16 + l15 + dx;
        int row = w + dy;
        int sb = row * 33 + (cl >> 1);
        bf[nf] = ((const half8*)inS)[sb * 8 + ((4 * (cl & 1) + l4) ^ (sb & 7))];
      }
#pragma unroll
      for (int mf = 0; mf < 4; mf++)
#pragma unroll
        for (int nf = 0; nf < 4; nf++)
          acc[mf][nf] = __builtin_amdgcn_mfma_f32_16x16x32_f16(a[mf], bf[nf], acc[mf][nf], 0, 0, 0);
    }
  }
  const int p_base = (y0 + w) * 64;
#pragma unroll
  for (int mf = 0; mf < 4; mf++) {
    const int ocb = o0 + mf * 16 + l4 * 4;
    const f32x4 bv = *(const f32x4*)(bias + ocb);
#pragma unroll
    for (int nf = 0; nf < 4; nf++) {
      const int p = p_base + nf * 16 + l15;
      if (mode == 0) {
        unsigned short h[4];
#pragma unroll
        for (int r = 0; r < 4; r++)
          h[r] = f2h(fmaxf(acc[mf][nf][r] + bv[r], 0.0f));
        unsigned long long pk = (unsigned long long)h[0] |
                                ((unsigned long long)h[1] << 16) |
                                ((unsigned long long)h[2] << 32) |
                                ((unsigned long long)h[3] << 48);
        *(unsigned long long*)(outT + ((size_t)b * 4096 + p) * 256 + ocb) = pk;
      } else {
#pragma unroll
        for (int r = 0; r < 4; r++)
          outN[((size_t)(b * 256 + ocb + r)) * HW + p] = acc[mf][nf][r] + bv[r];
      }
    }
  }
}

// ---------------- attention pass 1a (R10, __expf) ---------------------------
__global__ __launch_bounds__(256) void attn_rowstats_part(
    const unsigned short* __restrict__ kT, const unsigned short* __restrict__ qT,
    float* __restrict__ Mp, float* __restrict__ Zp) {
  __shared__ int4 qs4[64][32];   // 32KB [t][c-granule], swizzled
  const int b  = blockIdx.x;
  const int r0 = blockIdx.y * 64;
  const int q  = blockIdx.z;
  const int tid = threadIdx.x;
  const int w = tid >> 6, l = tid & 63;
  const int l4 = l >> 4, l15 = l & 15;
  const int4* qT4 = (const int4*)qT + (size_t)b * HW * 32;
  const half8* kT8 = (const half8*)kT + ((size_t)b * HW + r0) * 32;
  half8 afr[4][8];               // all 64 rows: [mfl][g]
#pragma unroll
  for (int mfl = 0; mfl < 4; mfl++)
#pragma unroll
    for (int g = 0; g < 8; g++)
      afr[mfl][g] = kT8[(size_t)(mfl * 16 + l15) * 32 + g * 4 + l4];
  float m[4][4], z[4][4];        // [mfl][reg]
#pragma unroll
  for (int i = 0; i < 4; i++)
#pragma unroll
    for (int j = 0; j < 4; j++) { m[i][j] = -1e30f; z[i][j] = 0.0f; }
  for (int t0 = q * 1024; t0 < q * 1024 + 1024; t0 += 64) {
    __syncthreads();
#pragma unroll
    for (int it = 0; it < 8; it++) {
      int id = tid + it * 256;
      int row = id >> 5, ch = id & 31;
      qs4[row][ch ^ (row & 7)] = qT4[(size_t)(t0 + row) * 32 + ch];
    }
    __syncthreads();
    f32x4 acc[4] = {{0.f,0.f,0.f,0.f},{0.f,0.f,0.f,0.f},
                    {0.f,0.f,0.f,0.f},{0.f,0.f,0.f,0.f}};
    const int t = w * 16 + l15;  // this wave's t-slice
#pragma unroll
    for (int g = 0; g < 8; g++) {
      half8 bq = ((const half8*)qs4)[t * 32 + ((g * 4 + l4) ^ (t & 7))];
#pragma unroll
      for (int mfl = 0; mfl < 4; mfl++)
        acc[mfl] = __builtin_amdgcn_mfma_f32_16x16x32_f16(afr[mfl][g], bq, acc[mfl], 0, 0, 0);
    }
#pragma unroll
    for (int mfl = 0; mfl < 4; mfl++)
#pragma unroll
      for (int r = 0; r < 4; r++) {
        float sv = acc[mfl][r];
        if (sv > m[mfl][r]) { z[mfl][r] *= __expf(m[mfl][r] - sv); m[mfl][r] = sv; }
        z[mfl][r] += __expf(sv - m[mfl][r]);
      }
  }
#pragma unroll
  for (int mfl = 0; mfl < 4; mfl++)
#pragma unroll
    for (int r = 0; r < 4; r++) {
      for (int off = 1; off < 16; off <<= 1) {
        float mo = __shfl_xor(m[mfl][r], off, 16);
        float zo = __shfl_xor(z[mfl][r], off, 16);
        float mn = fmaxf(m[mfl][r], mo);
        z[mfl][r] = z[mfl][r] * __expf(m[mfl][r] - mn) + zo * __expf(mo - mn);
        m[mfl][r] = mn;
      }
    }
  if (l15 == 0) {
#pragma unroll
    for (int mfl = 0; mfl < 4; mfl++)
#pragma unroll
      for (int r = 0; r < 4; r++) {
        int rr = r0 + mfl * 16 + l4 * 4 + r;
        Mp[((size_t)b * HW + rr) * 16 + q * 4 + w] = m[mfl][r];
        Zp[((size_t)b * HW + rr) * 16 + q * 4 + w] = z[mfl][r];
      }
  }
}

// ---------------- attention pass 1b: merge 16 partials (R10) ----------------
__global__ __launch_bounds__(256) void reduce_mz(
    const float* __restrict__ Mp, const float* __restrict__ Zp,
    float* __restrict__ Mrow, float* __restrict__ Zrow) {
  int i = blockIdx.x * 256 + threadIdx.x;      // 0 .. 8*4096-1
  float mq[16], zq[16];
#pragma unroll
  for (int j = 0; j < 4; j++) {
    float4 mv = *(const float4*)(Mp + (size_t)i * 16 + j * 4);
    float4 zv = *(const float4*)(Zp + (size_t)i * 16 + j * 4);
    mq[j*4+0] = mv.x; mq[j*4+1] = mv.y; mq[j*4+2] = mv.z; mq[j*4+3] = mv.w;
    zq[j*4+0] = zv.x; zq[j*4+1] = zv.y; zq[j*4+2] = zv.z; zq[j*4+3] = zv.w;
  }
  float M = mq[0];
#pragma unroll
  for (int j = 1; j < 16; j++) M = fmaxf(M, mq[j]);
  float Z = 0.0f;
#pragma unroll
  for (int j = 0; j < 16; j++) Z += zq[j] * __expf(mq[j] - M);
  Mrow[i] = M;
  Zrow[i] = 1.0f / Z;
}

// ---------------- attention pass 2: producer/consumer waves -----------------
// role = (w + 2*(blockIdx.y&1)) & 3. Roles 0,1: producers (S-MFMA 64 rows
// each + exp + psb[i&1] write). Roles 2,3: consumers (V load + PV from
// psb[(i-1)&1], 128 channels each, one iter behind). One barrier per iter.
__global__ __launch_bounds__(256, 2) void attn_pass2(
    const unsigned short* __restrict__ kT, const unsigned short* __restrict__ qT,
    const unsigned short* __restrict__ vB, const float* __restrict__ Mrow,
    const float* __restrict__ Zrow, const float* __restrict__ alphap,
    const float* __restrict__ betap, float* __restrict__ out) {
  __shared__ int4 qs4[64][32];      // 32KB Q [t][c-granule], swizzled
  __shared__ int4 ps4[2][64][16];   // 2x16KB P [t][r-granule], swizzled
  const int b  = blockIdx.x;
  const int t0 = blockIdx.y * 64;
  const int tid = threadIdx.x;
  const int w = tid >> 6, l = tid & 63;
  const int l4 = l >> 4, l15 = l & 15;
  const int role = (w + ((blockIdx.y & 1) << 1)) & 3;
  const int4*  qT4 = (const int4*)qT + ((size_t)b * HW + t0) * 32;
  const half8* kT8 = (const half8*)kT + (size_t)b * HW * 32;
  const half8* vB8 = (const half8*)vB + (size_t)b * 256 * 512;
  const float* Mb = Mrow + (size_t)b * HW;
  const float* Zb = Zrow + (size_t)b * HW;
  // stage Q once (all waves)
#pragma unroll
  for (int it = 0; it < 8; it++) {
    int id = tid + it * 256;
    int row = id >> 5, ch = id & 31;
    qs4[row][ch ^ (row & 7)] = qT4[(size_t)row * 32 + ch];
  }
  __syncthreads();

  if (role < 2) {
    // ================= producer: S + exp -> psb =================
    const int p = role;
#pragma unroll 1
    for (int iter = 0; iter < 32; iter++) {
      const int r0 = iter * 128;
      unsigned long long* pw = (unsigned long long*)&ps4[iter & 1][0][0];
      f32x4 acc_s[4][4];
#pragma unroll
      for (int i = 0; i < 4; i++)
#pragma unroll
        for (int j = 0; j < 4; j++) acc_s[i][j] = {0.f, 0.f, 0.f, 0.f};
#pragma unroll
      for (int mh = 0; mh < 2; mh++) {
        half8 ak0[8], ak1[8];
#pragma unroll
        for (int g = 0; g < 8; g++) {
          ak0[g] = kT8[(size_t)(r0 + p * 64 + mh * 32 + l15) * 32 + g * 4 + l4];
          ak1[g] = kT8[(size_t)(r0 + p * 64 + mh * 32 + 16 + l15) * 32 + g * 4 + l4];
        }
#pragma unroll
        for (int g = 0; g < 8; g++) {
          half8 bq[4];
#pragma unroll
          for (int nf = 0; nf < 4; nf++) {
            int t = nf * 16 + l15;
            bq[nf] = ((const half8*)qs4)[t * 32 + ((g * 4 + l4) ^ (t & 7))];
          }
#pragma unroll
          for (int nf = 0; nf < 4; nf++) {
            acc_s[mh * 2][nf]     = __builtin_amdgcn_mfma_f32_16x16x32_f16(ak0[g], bq[nf], acc_s[mh * 2][nf], 0, 0, 0);
            acc_s[mh * 2 + 1][nf] = __builtin_amdgcn_mfma_f32_16x16x32_f16(ak1[g], bq[nf], acc_s[mh * 2 + 1][nf], 0, 0, 0);
          }
        }
      }
      // exp + packed write: rows r0 + p*64 + mfl*16 + l4*4 + reg
#pragma unroll
      for (int mfl = 0; mfl < 4; mfl++) {
        int rbase = r0 + p * 64 + mfl * 16 + l4 * 4;
        f32x4 Mv = *(const f32x4*)(Mb + rbase);
        f32x4 Zv = *(const f32x4*)(Zb + rbase);
        int slot = p * 16 + mfl * 4 + l4;
#pragma unroll
        for (int nf = 0; nf < 4; nf++) {
          int t = nf * 16 + l15;
          unsigned lo = (unsigned)f2h(__expf(acc_s[mfl][nf][0] - Mv[0]) * Zv[0])
                      | ((unsigned)f2h(__expf(acc_s[mfl][nf][1] - Mv[1]) * Zv[1]) << 16);
          unsigned hi = (unsigned)f2h(__expf(acc_s[mfl][nf][2] - Mv[2]) * Zv[2])
                      | ((unsigned)f2h(__expf(acc_s[mfl][nf][3] - Mv[3]) * Zv[3]) << 16);
          int ch = slot >> 1;
          int fslot = ((ch ^ (t & 7)) << 1) | (slot & 1);
          pw[(size_t)t * 32 + fslot] =
              ((unsigned long long)hi << 32) | (unsigned long long)lo;
        }
      }
      __syncthreads();
    }
    // producers done (no output)
  } else {
    // ================= consumer: V load + PV (one iter behind) =================
    const int cq = role & 1;
    f32x4 acc_o[8][4];
#pragma unroll
    for (int i = 0; i < 8; i++)
#pragma unroll
      for (int j = 0; j < 4; j++) acc_o[i][j] = {0.f, 0.f, 0.f, 0.f};
#pragma unroll 1
    for (int iter = 0; iter < 32; iter++) {
      if (iter > 0) {
        const int r0p = (iter - 1) * 128;
        const half8* pr = (const half8*)&ps4[(iter - 1) & 1][0][0];
#pragma unroll
        for (int ks = 0; ks < 4; ks++) {
          half8 av[8];
#pragma unroll
          for (int cf = 0; cf < 8; cf++) {
            int c = cq * 128 + cf * 16 + l15;
            av[cf] = vB8[(size_t)c * 512 + (r0p >> 3) + ks * 4 + l4];
          }
#pragma unroll
          for (int nf = 0; nf < 4; nf++) {
            int t = nf * 16 + l15;
            half8 bp = pr[t * 16 + ((ks * 4 + l4) ^ (t & 7))];
#pragma unroll
            for (int cf = 0; cf < 8; cf++)
              acc_o[cf][nf] = __builtin_amdgcn_mfma_f32_16x16x32_f16(av[cf], bp, acc_o[cf][nf], 0, 0, 0);
          }
        }
      }
      __syncthreads();
    }
    // final PV(31): psb[31&1] = ps4[1]
    {
      const int r0p = 31 * 128;
      const half8* pr = (const half8*)&ps4[1][0][0];
#pragma unroll
      for (int ks = 0; ks < 4; ks++) {
        half8 av[8];
#pragma unroll
        for (int cf = 0; cf < 8; cf++) {
          int c = cq * 128 + cf * 16 + l15;
          av[cf] = vB8[(size_t)c * 512 + (r0p >> 3) + ks * 4 + l4];
        }
#pragma unroll
        for (int nf = 0; nf < 4; nf++) {
          int t = nf * 16 + l15;
          half8 bp = pr[t * 16 + ((ks * 4 + l4) ^ (t & 7))];
#pragma unroll
          for (int cf = 0; cf < 8; cf++)
            acc_o[cf][nf] = __builtin_amdgcn_mfma_f32_16x16x32_f16(av[cf], bp, acc_o[cf][nf], 0, 0, 0);
        }
      }
    }
    // epilogue: out = alpha*cb + beta*attn (cb already in out)
    const float alpha = alphap[0], beta = betap[0];
#pragma unroll
    for (int cf = 0; cf < 8; cf++) {
      int cbase = cq * 128 + cf * 16 + l4 * 4;
#pragma unroll
      for (int nf = 0; nf < 4; nf++) {
        int t = t0 + nf * 16 + l15;
#pragma unroll
        for (int r = 0; r < 4; r++) {
          size_t idx = ((size_t)(b * 256 + cbase + r)) * HW + t;
          out[idx] = alpha * out[idx] + beta * acc_o[cf][nf][r];
        }
      }
    }
  }
}

extern "C" void kernel_launch(void* const* d_in, const int* in_sizes, int n_in,
                              void* d_out, int out_size, void* d_ws, size_t ws_size,
                              hipStream_t stream) {
  (void)in_sizes; (void)n_in; (void)out_size; (void)ws_size;
  const float* x   = (const float*)d_in[0];
  const float* w1  = (const float*)d_in[1];
  const float* b1  = (const float*)d_in[2];
  const float* w2  = (const float*)d_in[3];
  const float* b2  = (const float*)d_in[4];
  const float* w3  = (const float*)d_in[5];
  const float* b3  = (const float*)d_in[6];
  const float* wb1 = (const float*)d_in[7];
  const float* bb1 = (const float*)d_in[8];
  const float* wb2 = (const float*)d_in[9];
  const float* bb2 = (const float*)d_in[10];
  const float* wq  = (const float*)d_in[11];
  const float* bq  = (const float*)d_in[12];
  const float* wk  = (const float*)d_in[13];
  const float* bk  = (const float*)d_in[14];
  const float* wv  = (const float*)d_in[15];
  const float* bv  = (const float*)d_in[16];
  const float* alpha = (const float*)d_in[17];
  const float* beta  = (const float*)d_in[18];
  float* out = (float*)d_out;

  const size_t SZH = (size_t)NB * 4096 * 256;   // 8,388,608 halves = 16MB
  unsigned short* wsh = (unsigned short*)d_ws;
  unsigned short* xh  = wsh;
  unsigned short* xfT = wsh + SZH;
  unsigned short* qT  = wsh + 2 * SZH;
  unsigned short* kT  = wsh + 3 * SZH;
  unsigned short* vN  = wsh + 4 * SZH;
  unsigned short* y1T = wsh + 5 * SZH;
  unsigned short* y2T = y1T + SZH / 4;
  unsigned short* t1T = wsh + 5 * SZH;
  float* Mrow = (float*)(wsh + 6 * SZH);
  float* Zrow = Mrow + (size_t)NB * HW;
  float* Mp   = Zrow + (size_t)NB * HW;         // [B*HW*16] partials
  float* Zp   = Mp + (size_t)NB * HW * 16;
  unsigned short* wh   = (unsigned short*)(Zp + (size_t)NB * HW * 16);
  unsigned short* w1h  = wh;
  unsigned short* w2h  = wh + 16384;
  unsigned short* w3h  = wh + 24576;
  unsigned short* wqh  = wh + 57344;            // [768][256] contiguous q|k|v
  unsigned short* wA1h = wh + 253952;
  unsigned short* wA2h = wA1h + (size_t)256 * 9 * 256;

  wcvt6<<<992, 256, 0, stream>>>(w1, w2, w3, wq, wk, wv, wh);
  wreorder<<<256, 256, 0, stream>>>(wb1, wA1h);
  wreorder<<<256, 256, 0, stream>>>(wb2, wA2h);
  transpose_cvt_h<<<dim3(8, 64, 4), 256, 0, stream>>>(x, xh);
  gemm1x1_h<<<dim3(8, 16, 1), 256, 0, stream>>>(w1h, b1, xh,  y1T, nullptr, 256,  64, 0, 1);
  gemm1x1_h<<<dim3(8, 16, 2), 256, 0, stream>>>(w2h, b2, y1T, y2T, nullptr,  64, 128, 0, 1);
  gemm1x1_h<<<dim3(8, 16, 4), 256, 0, stream>>>(w3h, b3, y2T, xfT, nullptr, 128, 256, 0, 1);
  gemm_qkv<<<dim3(8, 16, 12), 256, 0, stream>>>(wqh, bq, bk, bv, xfT, qT, kT, vN);
  conv3x3_mfma<<<dim3(8, 16, 4), 256, 0, stream>>>(xfT, wA1h, bb1, t1T, nullptr, 0);
  conv3x3_mfma<<<dim3(8, 16, 4), 256, 0, stream>>>(t1T, wA2h, bb2, nullptr, out, 1);
  attn_rowstats_part<<<dim3(8, 64, 4), 256, 0, stream>>>(kT, qT, Mp, Zp);
  reduce_mz<<<128, 256, 0, stream>>>(Mp, Zp, Mrow, Zrow);
  attn_pass2<<<dim3(8, 64), 256, 0, stream>>>(kT, qT, vN, Mrow, Zrow,
                                              alpha, beta, out);
}

// Round 14
// 549.612 us; speedup vs baseline: 1.2039x; 1.0461x over previous
//
#include <hip/hip_runtime.h>
#include <cstdint>

// AttCM R13: exact restore of R10 (best measured: 549.6us). Eight pass2
// schedule variants (R3,R5,R6,R7,R9,R11,R12) all land 275-301us; pipe-sum
// arithmetic (MFMA 66 + LDS ~95 + VMEM 60 + VALU ~40 per-CU) matches the
// measured floor. pass2 = R6-exact; rowstats = t-sliced waves, K in regs;
// QKV fused; convs/front = R3-proven fp16 MFMA.
// Shapes: B=8, C=256, HW=4096.

#define HW 4096
#define NB 8

typedef __attribute__((ext_vector_type(8))) _Float16 half8;    // 8 fp16 = 4 VGPR
typedef __attribute__((ext_vector_type(4))) float f32x4;       // MFMA C/D

static __device__ __forceinline__ unsigned short f2h(float x) {
  _Float16 h = (_Float16)x;
  return __builtin_bit_cast(unsigned short, h);
}

// ---------------- 1x1 weights fp32 -> fp16, all six packed ----------------
__global__ __launch_bounds__(256) void wcvt6(
    const float* __restrict__ w1, const float* __restrict__ w2,
    const float* __restrict__ w3, const float* __restrict__ wq,
    const float* __restrict__ wk, const float* __restrict__ wv,
    unsigned short* __restrict__ dst) {
  int i = blockIdx.x * 256 + threadIdx.x;
  const float* src; int off;
  if      (i <  16384) { src = w1; off = 0; }
  else if (i <  24576) { src = w2; off = 16384; }
  else if (i <  57344) { src = w3; off = 24576; }
  else if (i < 122880) { src = wq; off = 57344; }
  else if (i < 188416) { src = wk; off = 122880; }
  else                 { src = wv; off = 188416; }
  dst[i] = f2h(src[i - off]);
}

// ---------------- conv weight reorder: OIHW fp32 -> [o][tap][c] fp16 --------
__global__ __launch_bounds__(256) void wreorder(
    const float* __restrict__ w, unsigned short* __restrict__ wA) {
  const int o = blockIdx.x;
  const int c = threadIdx.x;
  const float* wp = w + ((size_t)o * 256 + c) * 9;
#pragma unroll
  for (int tap = 0; tap < 9; tap++)
    wA[((size_t)o * 9 + tap) * 256 + c] = f2h(wp[tap]);
}

// ---------------- fp32 [b][c][p] -> fp16 transposed [b][p][c] ----------------
__global__ __launch_bounds__(256) void transpose_cvt_h(
    const float* __restrict__ in, unsigned short* __restrict__ outT) {
  __shared__ float Ts[64][65];
  const int b  = blockIdx.x;
  const int t0 = blockIdx.y * 64;
  const int c0 = blockIdx.z * 64;
  const int tid = threadIdx.x;
#pragma unroll
  for (int it = 0; it < 4; it++) {
    int id = tid + it * 256;
    int c = id >> 4, f4 = id & 15;
    float4 v = *(const float4*)(in + ((size_t)(b * 256 + c0 + c)) * HW + t0 + f4 * 4);
    Ts[c][f4 * 4 + 0] = v.x; Ts[c][f4 * 4 + 1] = v.y;
    Ts[c][f4 * 4 + 2] = v.z; Ts[c][f4 * 4 + 3] = v.w;
  }
  __syncthreads();
#pragma unroll
  for (int it = 0; it < 2; it++) {
    int id = tid + it * 256;
    int t = id >> 3, ch = id & 7;
    unsigned short h[8];
#pragma unroll
    for (int e = 0; e < 8; e++) h[e] = f2h(Ts[ch * 8 + e][t]);
    int4 pk;
    pk.x = (int)((unsigned)h[0] | ((unsigned)h[1] << 16));
    pk.y = (int)((unsigned)h[2] | ((unsigned)h[3] << 16));
    pk.z = (int)((unsigned)h[4] | ((unsigned)h[5] << 16));
    pk.w = (int)((unsigned)h[6] | ((unsigned)h[7] << 16));
    ((int4*)outT)[((size_t)b * HW + t0 + t) * 32 + (c0 >> 3) + ch] = pk;
  }
}

// ---------------- 1x1 conv: fp16 MFMA GEMM, fused layout epilogue ----------
__global__ __launch_bounds__(256) void gemm1x1_h(
    const unsigned short* __restrict__ Wh,   // fp16 [M][K]
    const float* __restrict__ bias,
    const unsigned short* __restrict__ Xt,   // fp16 [b][4096][K]
    unsigned short* __restrict__ outT,
    unsigned short* __restrict__ outN,
    int K, int M, int mode, int doRelu) {
  __shared__ int4 WsL[64 * 32];
  __shared__ int4 XsL[128 * 8];
  const int b  = blockIdx.x;
  const int p0 = blockIdx.y * 256;
  const int m0 = blockIdx.z * 64;
  const int tid = threadIdx.x;
  const int w = tid >> 6, l = tid & 63;
  const int l4 = l >> 4, l15 = l & 15;
  const int KG  = K >> 3;
  const int kgl = (K >= 256) ? 5 : (K >= 128) ? 4 : 3;
  const int4* Wh4 = (const int4*)Wh;
  const int4* Xt4 = (const int4*)Xt + (size_t)(b * 4096 + p0) * KG;
  for (int id = tid; id < 64 * KG; id += 256) {
    int row = id >> kgl, g = id & (KG - 1);
    WsL[row * KG + (g ^ (row & 7))] = Wh4[(size_t)(m0 + row) * KG + g];
  }
  f32x4 acc[4][4];
#pragma unroll
  for (int i = 0; i < 4; i++)
#pragma unroll
    for (int j = 0; j < 4; j++) acc[i][j] = {0.f, 0.f, 0.f, 0.f};
  const int NCC = K >> 5;
  for (int cc = 0; cc < NCC; cc++) {
    __syncthreads();
#pragma unroll
    for (int it = 0; it < 4; it++) {
      int id = tid + it * 256;
      int p = id >> 2, ch = id & 3;
      XsL[(p >> 1) * 8 + ((((p & 1) << 2) + ch) ^ ((p >> 1) & 7))] =
          Xt4[(size_t)p * KG + cc * 4 + ch];
    }
    __syncthreads();
    half8 a[4], bx[4];
#pragma unroll
    for (int mf = 0; mf < 4; mf++) {
      int m = mf * 16 + l15;
      a[mf] = ((const half8*)WsL)[m * KG + ((cc * 4 + l4) ^ (m & 7))];
    }
#pragma unroll
    for (int nf = 0; nf < 4; nf++) {
      int p = w * 64 + nf * 16 + l15;
      bx[nf] = ((const half8*)XsL)[(p >> 1) * 8 + ((((p & 1) << 2) + l4) ^ ((p >> 1) & 7))];
    }
#pragma unroll
    for (int mf = 0; mf < 4; mf++)
#pragma unroll
      for (int nf = 0; nf < 4; nf++)
        acc[mf][nf] = __builtin_amdgcn_mfma_f32_16x16x32_f16(a[mf], bx[nf], acc[mf][nf], 0, 0, 0);
  }
#pragma unroll
  for (int mf = 0; mf < 4; mf++) {
    const int mrow = m0 + mf * 16 + l4 * 4;
    const f32x4 bv = *(const f32x4*)(bias + mrow);
#pragma unroll
    for (int nf = 0; nf < 4; nf++) {
      const int p = p0 + w * 64 + nf * 16 + l15;
      float vr[4];
#pragma unroll
      for (int r = 0; r < 4; r++) {
        float v = acc[mf][nf][r] + bv[r];
        if (doRelu) v = fmaxf(v, 0.0f);
        vr[r] = v;
      }
      if (mode == 0) {
        unsigned long long pk = (unsigned long long)f2h(vr[0]) |
                                ((unsigned long long)f2h(vr[1]) << 16) |
                                ((unsigned long long)f2h(vr[2]) << 32) |
                                ((unsigned long long)f2h(vr[3]) << 48);
        *(unsigned long long*)(outT + ((size_t)b * 4096 + p) * M + mrow) = pk;
      } else {
#pragma unroll
        for (int r = 0; r < 4; r++)
          outN[((size_t)(b * M + mrow + r)) * 4096 + p] = f2h(vr[r]);
      }
    }
  }
}

// ---------------- fused QKV gemm: M=768 stacked weights, routed epilogue ----
__global__ __launch_bounds__(256) void gemm_qkv(
    const unsigned short* __restrict__ W768,  // fp16 [768][256] (wq|wk|wv)
    const float* __restrict__ bq, const float* __restrict__ bk,
    const float* __restrict__ bv_, const unsigned short* __restrict__ Xt,
    unsigned short* __restrict__ qT, unsigned short* __restrict__ kTo,
    unsigned short* __restrict__ vN) {
  __shared__ int4 WsL[64 * 32];
  __shared__ int4 XsL[128 * 8];
  const int b  = blockIdx.x;
  const int p0 = blockIdx.y * 256;
  const int z  = blockIdx.z;
  const int sel = z >> 2;
  const int m0 = (z & 3) * 64;
  const float* bias = (sel == 0) ? bq : (sel == 1) ? bk : bv_;
  const int tid = threadIdx.x;
  const int w = tid >> 6, l = tid & 63;
  const int l4 = l >> 4, l15 = l & 15;
  const int4* Wh4 = (const int4*)W768 + (size_t)sel * 256 * 32;
  const int4* Xt4 = (const int4*)Xt + (size_t)(b * 4096 + p0) * 32;
  for (int id = tid; id < 64 * 32; id += 256) {
    int row = id >> 5, g = id & 31;
    WsL[row * 32 + (g ^ (row & 7))] = Wh4[(size_t)(m0 + row) * 32 + g];
  }
  f32x4 acc[4][4];
#pragma unroll
  for (int i = 0; i < 4; i++)
#pragma unroll
    for (int j = 0; j < 4; j++) acc[i][j] = {0.f, 0.f, 0.f, 0.f};
  for (int cc = 0; cc < 8; cc++) {
    __syncthreads();
#pragma unroll
    for (int it = 0; it < 4; it++) {
      int id = tid + it * 256;
      int p = id >> 2, ch = id & 3;
      XsL[(p >> 1) * 8 + ((((p & 1) << 2) + ch) ^ ((p >> 1) & 7))] =
          Xt4[(size_t)p * 32 + cc * 4 + ch];
    }
    __syncthreads();
    half8 a[4], bx[4];
#pragma unroll
    for (int mf = 0; mf < 4; mf++) {
      int m = mf * 16 + l15;
      a[mf] = ((const half8*)WsL)[m * 32 + ((cc * 4 + l4) ^ (m & 7))];
    }
#pragma unroll
    for (int nf = 0; nf < 4; nf++) {
      int p = w * 64 + nf * 16 + l15;
      bx[nf] = ((const half8*)XsL)[(p >> 1) * 8 + ((((p & 1) << 2) + l4) ^ ((p >> 1) & 7))];
    }
#pragma unroll
    for (int mf = 0; mf < 4; mf++)
#pragma unroll
      for (int nf = 0; nf < 4; nf++)
        acc[mf][nf] = __builtin_amdgcn_mfma_f32_16x16x32_f16(a[mf], bx[nf], acc[mf][nf], 0, 0, 0);
  }
  unsigned short* outT = (sel == 0) ? qT : kTo;
#pragma unroll
  for (int mf = 0; mf < 4; mf++) {
    const int mrow = m0 + mf * 16 + l4 * 4;
    const f32x4 bvv = *(const f32x4*)(bias + mrow);
#pragma unroll
    for (int nf = 0; nf < 4; nf++) {
      const int p = p0 + w * 64 + nf * 16 + l15;
      float vr[4];
#pragma unroll
      for (int r = 0; r < 4; r++) vr[r] = acc[mf][nf][r] + bvv[r];
      if (sel < 2) {
        unsigned long long pk = (unsigned long long)f2h(vr[0]) |
                                ((unsigned long long)f2h(vr[1]) << 16) |
                                ((unsigned long long)f2h(vr[2]) << 32) |
                                ((unsigned long long)f2h(vr[3]) << 48);
        *(unsigned long long*)(outT + ((size_t)b * 4096 + p) * 256 + mrow) = pk;
      } else {
#pragma unroll
        for (int r = 0; r < 4; r++)
          vN[((size_t)(b * 256 + mrow + r)) * 4096 + p] = f2h(vr[r]);
      }
    }
  }
}

// ---------------- 3x3 conv, fp16 MFMA implicit GEMM ------------------------
__global__ __launch_bounds__(256, 2) void conv3x3_mfma(
    const unsigned short* __restrict__ inT,
    const unsigned short* __restrict__ wA,
    const float* __restrict__ bias,
    unsigned short* __restrict__ outT,
    float* __restrict__ outN,
    int mode) {
  __shared__ int4 wS[2304];
  __shared__ int4 inS[1584];
  const int b  = blockIdx.x;
  const int y0 = blockIdx.y * 4;
  const int o0 = blockIdx.z * 64;
  const int tid = threadIdx.x;
  const int w = tid >> 6, l = tid & 63;
  const int l4 = l >> 4, l15 = l & 15;
  const int4* inT4 = (const int4*)inT + (size_t)b * 4096 * 32;
  const int4* wA4  = (const int4*)wA;
  f32x4 acc[4][4];
#pragma unroll
  for (int i = 0; i < 4; i++)
#pragma unroll
    for (int j = 0; j < 4; j++) acc[i][j] = {0.f, 0.f, 0.f, 0.f};

  for (int c0 = 0; c0 < 256; c0 += 32) {
    __syncthreads();
#pragma unroll
    for (int it = 0; it < 9; it++) {
      int id = it * 256 + tid;
      int ch = id & 3;
      int r  = id >> 2;
      int tap = r % 9, ol = r / 9;
      int sbw = tap * 32 + (ol >> 1);
      int slot = (4 * (ol & 1) + ch) ^ (sbw & 7);
      wS[sbw * 8 + slot] = wA4[((size_t)(o0 + ol) * 9 + tap) * 32 + (c0 >> 3) + ch];
    }
#pragma unroll
    for (int it = 0; it < 6; it++) {
      int ch = tid & 3;
      int col = tid >> 2;
      int yimg = y0 + it - 1;
      int4 v = {0, 0, 0, 0};
      if (yimg >= 0 && yimg < 64)
        v = inT4[(size_t)(yimg * 64 + col) * 32 + (c0 >> 3) + ch];
      int cl = col + 1;
      int sb = it * 33 + (cl >> 1);
      int slot = (4 * (cl & 1) + ch) ^ (sb & 7);
      inS[sb * 8 + slot] = v;
    }
    if (tid < 48) {
      int row = tid >> 3;
      int cl = ((tid >> 2) & 1) ? 65 : 0;
      int ch = tid & 3;
      int sb = row * 33 + (cl >> 1);
      int slot = (4 * (cl & 1) + ch) ^ (sb & 7);
      inS[sb * 8 + slot] = {0, 0, 0, 0};
    }
    __syncthreads();
#pragma unroll
    for (int tap = 0; tap < 9; tap++) {
      const int dy = tap / 3, dx = tap % 3;
      half8 a[4], bf[4];
#pragma unroll
      for (int mf = 0; mf < 4; mf++) {
        int oc = mf * 16 + l15;
        int sbw = tap * 32 + (oc >> 1);
        a[mf] = ((const half8*)wS)[sbw * 8 + ((4 * (oc & 1) + l4) ^ (sbw & 7))];
      }
#pragma unroll
      for (int nf = 0; nf < 4; nf++) {
        int cl = nf * 16 + l15 + dx;
        int row = w + dy;
        int sb = row * 33 + (cl >> 1);
        bf[nf] = ((const half8*)inS)[sb * 8 + ((4 * (cl & 1) + l4) ^ (sb & 7))];
      }
#pragma unroll
      for (int mf = 0; mf < 4; mf++)
#pragma unroll
        for (int nf = 0; nf < 4; nf++)
          acc[mf][nf] = __builtin_amdgcn_mfma_f32_16x16x32_f16(a[mf], bf[nf], acc[mf][nf], 0, 0, 0);
    }
  }
  const int p_base = (y0 + w) * 64;
#pragma unroll
  for (int mf = 0; mf < 4; mf++) {
    const int ocb = o0 + mf * 16 + l4 * 4;
    const f32x4 bv = *(const f32x4*)(bias + ocb);
#pragma unroll
    for (int nf = 0; nf < 4; nf++) {
      const int p = p_base + nf * 16 + l15;
      if (mode == 0) {
        unsigned short h[4];
#pragma unroll
        for (int r = 0; r < 4; r++)
          h[r] = f2h(fmaxf(acc[mf][nf][r] + bv[r], 0.0f));
        unsigned long long pk = (unsigned long long)h[0] |
                                ((unsigned long long)h[1] << 16) |
                                ((unsigned long long)h[2] << 32) |
                                ((unsigned long long)h[3] << 48);
        *(unsigned long long*)(outT + ((size_t)b * 4096 + p) * 256 + ocb) = pk;
      } else {
#pragma unroll
        for (int r = 0; r < 4; r++)
          outN[((size_t)(b * 256 + ocb + r)) * HW + p] = acc[mf][nf][r] + bv[r];
      }
    }
  }
}

// ---------------- attention pass 1a: t-sliced waves, K fully in regs --------
__global__ __launch_bounds__(256) void attn_rowstats_part(
    const unsigned short* __restrict__ kT, const unsigned short* __restrict__ qT,
    float* __restrict__ Mp, float* __restrict__ Zp) {
  __shared__ int4 qs4[64][32];   // 32KB [t][c-granule], swizzled
  const int b  = blockIdx.x;
  const int r0 = blockIdx.y * 64;
  const int q  = blockIdx.z;
  const int tid = threadIdx.x;
  const int w = tid >> 6, l = tid & 63;
  const int l4 = l >> 4, l15 = l & 15;
  const int4* qT4 = (const int4*)qT + (size_t)b * HW * 32;
  const half8* kT8 = (const half8*)kT + ((size_t)b * HW + r0) * 32;
  half8 afr[4][8];               // all 64 rows: [mfl][g]
#pragma unroll
  for (int mfl = 0; mfl < 4; mfl++)
#pragma unroll
    for (int g = 0; g < 8; g++)
      afr[mfl][g] = kT8[(size_t)(mfl * 16 + l15) * 32 + g * 4 + l4];
  float m[4][4], z[4][4];        // [mfl][reg]
#pragma unroll
  for (int i = 0; i < 4; i++)
#pragma unroll
    for (int j = 0; j < 4; j++) { m[i][j] = -1e30f; z[i][j] = 0.0f; }
  for (int t0 = q * 1024; t0 < q * 1024 + 1024; t0 += 64) {
    __syncthreads();
#pragma unroll
    for (int it = 0; it < 8; it++) {
      int id = tid + it * 256;
      int row = id >> 5, ch = id & 31;
      qs4[row][ch ^ (row & 7)] = qT4[(size_t)(t0 + row) * 32 + ch];
    }
    __syncthreads();
    f32x4 acc[4] = {{0.f,0.f,0.f,0.f},{0.f,0.f,0.f,0.f},
                    {0.f,0.f,0.f,0.f},{0.f,0.f,0.f,0.f}};
    const int t = w * 16 + l15;  // this wave's t-slice
#pragma unroll
    for (int g = 0; g < 8; g++) {
      half8 bq = ((const half8*)qs4)[t * 32 + ((g * 4 + l4) ^ (t & 7))];
#pragma unroll
      for (int mfl = 0; mfl < 4; mfl++)
        acc[mfl] = __builtin_amdgcn_mfma_f32_16x16x32_f16(afr[mfl][g], bq, acc[mfl], 0, 0, 0);
    }
#pragma unroll
    for (int mfl = 0; mfl < 4; mfl++)
#pragma unroll
      for (int r = 0; r < 4; r++) {
        float sv = acc[mfl][r];
        if (sv > m[mfl][r]) { z[mfl][r] *= __expf(m[mfl][r] - sv); m[mfl][r] = sv; }
        z[mfl][r] += __expf(sv - m[mfl][r]);
      }
  }
#pragma unroll
  for (int mfl = 0; mfl < 4; mfl++)
#pragma unroll
    for (int r = 0; r < 4; r++) {
      for (int off = 1; off < 16; off <<= 1) {
        float mo = __shfl_xor(m[mfl][r], off, 16);
        float zo = __shfl_xor(z[mfl][r], off, 16);
        float mn = fmaxf(m[mfl][r], mo);
        z[mfl][r] = z[mfl][r] * __expf(m[mfl][r] - mn) + zo * __expf(mo - mn);
        m[mfl][r] = mn;
      }
    }
  if (l15 == 0) {
#pragma unroll
    for (int mfl = 0; mfl < 4; mfl++)
#pragma unroll
      for (int r = 0; r < 4; r++) {
        int rr = r0 + mfl * 16 + l4 * 4 + r;
        Mp[((size_t)b * HW + rr) * 16 + q * 4 + w] = m[mfl][r];
        Zp[((size_t)b * HW + rr) * 16 + q * 4 + w] = z[mfl][r];
      }
  }
}

// ---------------- attention pass 1b: merge 16 partials ----------------------
__global__ __launch_bounds__(256) void reduce_mz(
    const float* __restrict__ Mp, const float* __restrict__ Zp,
    float* __restrict__ Mrow, float* __restrict__ Zrow) {
  int i = blockIdx.x * 256 + threadIdx.x;      // 0 .. 8*4096-1
  float mq[16], zq[16];
#pragma unroll
  for (int j = 0; j < 4; j++) {
    float4 mv = *(const float4*)(Mp + (size_t)i * 16 + j * 4);
    float4 zv = *(const float4*)(Zp + (size_t)i * 16 + j * 4);
    mq[j*4+0] = mv.x; mq[j*4+1] = mv.y; mq[j*4+2] = mv.z; mq[j*4+3] = mv.w;
    zq[j*4+0] = zv.x; zq[j*4+1] = zv.y; zq[j*4+2] = zv.z; zq[j*4+3] = zv.w;
  }
  float M = mq[0];
#pragma unroll
  for (int j = 1; j < 16; j++) M = fmaxf(M, mq[j]);
  float Z = 0.0f;
#pragma unroll
  for (int j = 0; j < 16; j++) Z += zq[j] * __expf(mq[j] - M);
  Mrow[i] = M;
  Zrow[i] = 1.0f / Z;
}

// ---------------- attention pass 2 (R6-exact): bp-once + early V preload ----
__global__ __launch_bounds__(256, 2) void attn_pass2(
    const unsigned short* __restrict__ kT, const unsigned short* __restrict__ qT,
    const unsigned short* __restrict__ vB, const float* __restrict__ Mrow,
    const float* __restrict__ Zrow, const float* __restrict__ alphap,
    const float* __restrict__ betap, float* __restrict__ out) {
  __shared__ int4 qs4[64][32];      // 32KB Q [t][c-granule], swizzled
  __shared__ int4 ps4[2][64][16];   // 2x16KB P [t][r-granule], swizzled
  const int b  = blockIdx.x;
  const int t0 = blockIdx.y * 64;
  const int tid = threadIdx.x;
  const int w = tid >> 6, l = tid & 63;
  const int l4 = l >> 4, l15 = l & 15;
  const int4*  qT4 = (const int4*)qT + ((size_t)b * HW + t0) * 32;
  const half8* kT8 = (const half8*)kT + (size_t)b * HW * 32;
  const half8* vB8 = (const half8*)vB + (size_t)b * 256 * 512;
  const float* Mb = Mrow + (size_t)b * HW;
  const float* Zb = Zrow + (size_t)b * HW;
#pragma unroll
  for (int it = 0; it < 8; it++) {
    int id = tid + it * 256;
    int row = id >> 5, ch = id & 31;
    qs4[row][ch ^ (row & 7)] = qT4[(size_t)row * 32 + ch];
  }
  f32x4 acc_o[4][4];
#pragma unroll
  for (int i = 0; i < 4; i++)
#pragma unroll
    for (int j = 0; j < 4; j++) acc_o[i][j] = {0.f, 0.f, 0.f, 0.f};
  __syncthreads();

#pragma unroll 1
  for (int iter = 0; iter < 32; iter++) {
    const int r0 = iter * 128;
    int4* psb = &ps4[iter & 1][0][0];
    half8 ak0[8], ak1[8];
#pragma unroll
    for (int g = 0; g < 8; g++) {
      ak0[g] = kT8[(size_t)(r0 + w * 32 + l15) * 32 + g * 4 + l4];
      ak1[g] = kT8[(size_t)(r0 + w * 32 + 16 + l15) * 32 + g * 4 + l4];
    }
    f32x4 acc_s[2][4];
#pragma unroll
    for (int i = 0; i < 2; i++)
#pragma unroll
      for (int j = 0; j < 4; j++) acc_s[i][j] = {0.f, 0.f, 0.f, 0.f};
#pragma unroll
    for (int g = 0; g < 8; g++) {
      half8 bq[4];
#pragma unroll
      for (int nf = 0; nf < 4; nf++) {
        int t = nf * 16 + l15;
        bq[nf] = ((const half8*)qs4)[t * 32 + ((g * 4 + l4) ^ (t & 7))];
      }
#pragma unroll
      for (int nf = 0; nf < 4; nf++) {
        acc_s[0][nf] = __builtin_amdgcn_mfma_f32_16x16x32_f16(ak0[g], bq[nf], acc_s[0][nf], 0, 0, 0);
        acc_s[1][nf] = __builtin_amdgcn_mfma_f32_16x16x32_f16(ak1[g], bq[nf], acc_s[1][nf], 0, 0, 0);
      }
    }
    half8 avr[4][4];   // [cc4][ks]
#pragma unroll
    for (int cc4 = 0; cc4 < 2; cc4++) {
      const int c = cc4 * 64 + w * 16 + l15;
#pragma unroll
      for (int ks = 0; ks < 4; ks++)
        avr[cc4][ks] = vB8[(size_t)c * 512 + (r0 >> 3) + ks * 4 + l4];
    }
#pragma unroll
    for (int mfl = 0; mfl < 2; mfl++) {
      int rbase = r0 + w * 32 + mfl * 16 + l4 * 4;
      f32x4 Mv = *(const f32x4*)(Mb + rbase);
      f32x4 Zv = *(const f32x4*)(Zb + rbase);
      int slot = w * 8 + mfl * 4 + l4;
#pragma unroll
      for (int nf = 0; nf < 4; nf++) {
        int t = nf * 16 + l15;
        unsigned lo = (unsigned)f2h(__expf(acc_s[mfl][nf][0] - Mv[0]) * Zv[0])
                    | ((unsigned)f2h(__expf(acc_s[mfl][nf][1] - Mv[1]) * Zv[1]) << 16);
        unsigned hi = (unsigned)f2h(__expf(acc_s[mfl][nf][2] - Mv[2]) * Zv[2])
                    | ((unsigned)f2h(__expf(acc_s[mfl][nf][3] - Mv[3]) * Zv[3]) << 16);
        int ch = slot >> 1;
        int fslot = ((ch ^ (t & 7)) << 1) | (slot & 1);
        ((unsigned long long*)psb)[(size_t)t * 32 + fslot] =
            ((unsigned long long)hi << 32) | (unsigned long long)lo;
      }
    }
    __syncthreads();
#pragma unroll
    for (int cc4 = 2; cc4 < 4; cc4++) {
      const int c = cc4 * 64 + w * 16 + l15;
#pragma unroll
      for (int ks = 0; ks < 4; ks++)
        avr[cc4][ks] = vB8[(size_t)c * 512 + (r0 >> 3) + ks * 4 + l4];
    }
#pragma unroll
    for (int ks = 0; ks < 4; ks++) {
#pragma unroll
      for (int nf = 0; nf < 4; nf++) {
        int t = nf * 16 + l15;
        half8 bp = ((const half8*)psb)[t * 16 + ((ks * 4 + l4) ^ (t & 7))];
#pragma unroll
        for (int cc4 = 0; cc4 < 4; cc4++)
          acc_o[cc4][nf] = __builtin_amdgcn_mfma_f32_16x16x32_f16(avr[cc4][ks], bp, acc_o[cc4][nf], 0, 0, 0);
      }
    }
  }
  const float alpha = alphap[0], beta = betap[0];
#pragma unroll
  for (int cc4 = 0; cc4 < 4; cc4++) {
    int cbase = cc4 * 64 + w * 16 + l4 * 4;
#pragma unroll
    for (int nf = 0; nf < 4; nf++) {
      int t = t0 + nf * 16 + l15;
#pragma unroll
      for (int r = 0; r < 4; r++) {
        size_t idx = ((size_t)(b * 256 + cbase + r)) * HW + t;
        out[idx] = alpha * out[idx] + beta * acc_o[cc4][nf][r];
      }
    }
  }
}

extern "C" void kernel_launch(void* const* d_in, const int* in_sizes, int n_in,
                              void* d_out, int out_size, void* d_ws, size_t ws_size,
                              hipStream_t stream) {
  (void)in_sizes; (void)n_in; (void)out_size; (void)ws_size;
  const float* x   = (const float*)d_in[0];
  const float* w1  = (const float*)d_in[1];
  const float* b1  = (const float*)d_in[2];
  const float* w2  = (const float*)d_in[3];
  const float* b2  = (const float*)d_in[4];
  const float* w3  = (const float*)d_in[5];
  const float* b3  = (const float*)d_in[6];
  const float* wb1 = (const float*)d_in[7];
  const float* bb1 = (const float*)d_in[8];
  const float* wb2 = (const float*)d_in[9];
  const float* bb2 = (const float*)d_in[10];
  const float* wq  = (const float*)d_in[11];
  const float* bq  = (const float*)d_in[12];
  const float* wk  = (const float*)d_in[13];
  const float* bk  = (const float*)d_in[14];
  const float* wv  = (const float*)d_in[15];
  const float* bv  = (const float*)d_in[16];
  const float* alpha = (const float*)d_in[17];
  const float* beta  = (const float*)d_in[18];
  float* out = (float*)d_out;

  const size_t SZH = (size_t)NB * 4096 * 256;   // 8,388,608 halves = 16MB
  unsigned short* wsh = (unsigned short*)d_ws;
  unsigned short* xh  = wsh;
  unsigned short* xfT = wsh + SZH;
  unsigned short* qT  = wsh + 2 * SZH;
  unsigned short* kT  = wsh + 3 * SZH;
  unsigned short* vN  = wsh + 4 * SZH;
  unsigned short* y1T = wsh + 5 * SZH;
  unsigned short* y2T = y1T + SZH / 4;
  unsigned short* t1T = wsh + 5 * SZH;
  float* Mrow = (float*)(wsh + 6 * SZH);
  float* Zrow = Mrow + (size_t)NB * HW;
  float* Mp   = Zrow + (size_t)NB * HW;         // [B*HW*16] partials
  float* Zp   = Mp + (size_t)NB * HW * 16;
  unsigned short* wh   = (unsigned short*)(Zp + (size_t)NB * HW * 16);
  unsigned short* w1h  = wh;
  unsigned short* w2h  = wh + 16384;
  unsigned short* w3h  = wh + 24576;
  unsigned short* wqh  = wh + 57344;            // [768][256] contiguous q|k|v
  unsigned short* wA1h = wh + 253952;
  unsigned short* wA2h = wA1h + (size_t)256 * 9 * 256;

  wcvt6<<<992, 256, 0, stream>>>(w1, w2, w3, wq, wk, wv, wh);
  wreorder<<<256, 256, 0, stream>>>(wb1, wA1h);
  wreorder<<<256, 256, 0, stream>>>(wb2, wA2h);
  transpose_cvt_h<<<dim3(8, 64, 4), 256, 0, stream>>>(x, xh);
  gemm1x1_h<<<dim3(8, 16, 1), 256, 0, stream>>>(w1h, b1, xh,  y1T, nullptr, 256,  64, 0, 1);
  gemm1x1_h<<<dim3(8, 16, 2), 256, 0, stream>>>(w2h, b2, y1T, y2T, nullptr,  64, 128, 0, 1);
  gemm1x1_h<<<dim3(8, 16, 4), 256, 0, stream>>>(w3h, b3, y2T, xfT, nullptr, 128, 256, 0, 1);
  gemm_qkv<<<dim3(8, 16, 12), 256, 0, stream>>>(wqh, bq, bk, bv, xfT, qT, kT, vN);
  conv3x3_mfma<<<dim3(8, 16, 4), 256, 0, stream>>>(xfT, wA1h, bb1, t1T, nullptr, 0);
  conv3x3_mfma<<<dim3(8, 16, 4), 256, 0, stream>>>(t1T, wA2h, bb2, nullptr, out, 1);
  attn_rowstats_part<<<dim3(8, 64, 4), 256, 0, stream>>>(kT, qT, Mp, Zp);
  reduce_mz<<<128, 256, 0, stream>>>(Mp, Zp, Mrow, Zrow);
  attn_pass2<<<dim3(8, 64), 256, 0, stream>>>(kT, qT, vN, Mrow, Zrow,
                                              alpha, beta, out);
}

// Round 16
// 548.768 us; speedup vs baseline: 1.2057x; 1.0015x over previous
//
#include <hip/hip_runtime.h>
#include <cstdint>

// AttCM R15 (FINAL): exact restore of the R10/R13 champion (549.6us, verified
// twice, absmax 3.05e-05). R14's S-materialization (268MB) overran ws_size ->
// reverted. Structure: fp16 MFMA everywhere; fused QKV; XCD-pinned grids;
// two-pass attention with R6 pass2 (bp-once + split V preload, dbuf P).
// Shapes: B=8, C=256, HW=4096.

#define HW 4096
#define NB 8

typedef __attribute__((ext_vector_type(8))) _Float16 half8;    // 8 fp16 = 4 VGPR
typedef __attribute__((ext_vector_type(4))) float f32x4;       // MFMA C/D

static __device__ __forceinline__ unsigned short f2h(float x) {
  _Float16 h = (_Float16)x;
  return __builtin_bit_cast(unsigned short, h);
}

// ---------------- 1x1 weights fp32 -> fp16, all six packed ----------------
__global__ __launch_bounds__(256) void wcvt6(
    const float* __restrict__ w1, const float* __restrict__ w2,
    const float* __restrict__ w3, const float* __restrict__ wq,
    const float* __restrict__ wk, const float* __restrict__ wv,
    unsigned short* __restrict__ dst) {
  int i = blockIdx.x * 256 + threadIdx.x;
  const float* src; int off;
  if      (i <  16384) { src = w1; off = 0; }
  else if (i <  24576) { src = w2; off = 16384; }
  else if (i <  57344) { src = w3; off = 24576; }
  else if (i < 122880) { src = wq; off = 57344; }
  else if (i < 188416) { src = wk; off = 122880; }
  else                 { src = wv; off = 188416; }
  dst[i] = f2h(src[i - off]);
}

// ---------------- conv weight reorder: OIHW fp32 -> [o][tap][c] fp16 --------
__global__ __launch_bounds__(256) void wreorder(
    const float* __restrict__ w, unsigned short* __restrict__ wA) {
  const int o = blockIdx.x;
  const int c = threadIdx.x;
  const float* wp = w + ((size_t)o * 256 + c) * 9;
#pragma unroll
  for (int tap = 0; tap < 9; tap++)
    wA[((size_t)o * 9 + tap) * 256 + c] = f2h(wp[tap]);
}

// ---------------- fp32 [b][c][p] -> fp16 transposed [b][p][c] ----------------
__global__ __launch_bounds__(256) void transpose_cvt_h(
    const float* __restrict__ in, unsigned short* __restrict__ outT) {
  __shared__ float Ts[64][65];
  const int b  = blockIdx.x;
  const int t0 = blockIdx.y * 64;
  const int c0 = blockIdx.z * 64;
  const int tid = threadIdx.x;
#pragma unroll
  for (int it = 0; it < 4; it++) {
    int id = tid + it * 256;
    int c = id >> 4, f4 = id & 15;
    float4 v = *(const float4*)(in + ((size_t)(b * 256 + c0 + c)) * HW + t0 + f4 * 4);
    Ts[c][f4 * 4 + 0] = v.x; Ts[c][f4 * 4 + 1] = v.y;
    Ts[c][f4 * 4 + 2] = v.z; Ts[c][f4 * 4 + 3] = v.w;
  }
  __syncthreads();
#pragma unroll
  for (int it = 0; it < 2; it++) {
    int id = tid + it * 256;
    int t = id >> 3, ch = id & 7;
    unsigned short h[8];
#pragma unroll
    for (int e = 0; e < 8; e++) h[e] = f2h(Ts[ch * 8 + e][t]);
    int4 pk;
    pk.x = (int)((unsigned)h[0] | ((unsigned)h[1] << 16));
    pk.y = (int)((unsigned)h[2] | ((unsigned)h[3] << 16));
    pk.z = (int)((unsigned)h[4] | ((unsigned)h[5] << 16));
    pk.w = (int)((unsigned)h[6] | ((unsigned)h[7] << 16));
    ((int4*)outT)[((size_t)b * HW + t0 + t) * 32 + (c0 >> 3) + ch] = pk;
  }
}

// ---------------- 1x1 conv: fp16 MFMA GEMM, fused layout epilogue ----------
__global__ __launch_bounds__(256) void gemm1x1_h(
    const unsigned short* __restrict__ Wh,   // fp16 [M][K]
    const float* __restrict__ bias,
    const unsigned short* __restrict__ Xt,   // fp16 [b][4096][K]
    unsigned short* __restrict__ outT,
    unsigned short* __restrict__ outN,
    int K, int M, int mode, int doRelu) {
  __shared__ int4 WsL[64 * 32];
  __shared__ int4 XsL[128 * 8];
  const int b  = blockIdx.x;
  const int p0 = blockIdx.y * 256;
  const int m0 = blockIdx.z * 64;
  const int tid = threadIdx.x;
  const int w = tid >> 6, l = tid & 63;
  const int l4 = l >> 4, l15 = l & 15;
  const int KG  = K >> 3;
  const int kgl = (K >= 256) ? 5 : (K >= 128) ? 4 : 3;
  const int4* Wh4 = (const int4*)Wh;
  const int4* Xt4 = (const int4*)Xt + (size_t)(b * 4096 + p0) * KG;
  for (int id = tid; id < 64 * KG; id += 256) {
    int row = id >> kgl, g = id & (KG - 1);
    WsL[row * KG + (g ^ (row & 7))] = Wh4[(size_t)(m0 + row) * KG + g];
  }
  f32x4 acc[4][4];
#pragma unroll
  for (int i = 0; i < 4; i++)
#pragma unroll
    for (int j = 0; j < 4; j++) acc[i][j] = {0.f, 0.f, 0.f, 0.f};
  const int NCC = K >> 5;
  for (int cc = 0; cc < NCC; cc++) {
    __syncthreads();
#pragma unroll
    for (int it = 0; it < 4; it++) {
      int id = tid + it * 256;
      int p = id >> 2, ch = id & 3;
      XsL[(p >> 1) * 8 + ((((p & 1) << 2) + ch) ^ ((p >> 1) & 7))] =
          Xt4[(size_t)p * KG + cc * 4 + ch];
    }
    __syncthreads();
    half8 a[4], bx[4];
#pragma unroll
    for (int mf = 0; mf < 4; mf++) {
      int m = mf * 16 + l15;
      a[mf] = ((const half8*)WsL)[m * KG + ((cc * 4 + l4) ^ (m & 7))];
    }
#pragma unroll
    for (int nf = 0; nf < 4; nf++) {
      int p = w * 64 + nf * 16 + l15;
      bx[nf] = ((const half8*)XsL)[(p >> 1) * 8 + ((((p & 1) << 2) + l4) ^ ((p >> 1) & 7))];
    }
#pragma unroll
    for (int mf = 0; mf < 4; mf++)
#pragma unroll
      for (int nf = 0; nf < 4; nf++)
        acc[mf][nf] = __builtin_amdgcn_mfma_f32_16x16x32_f16(a[mf], bx[nf], acc[mf][nf], 0, 0, 0);
  }
#pragma unroll
  for (int mf = 0; mf < 4; mf++) {
    const int mrow = m0 + mf * 16 + l4 * 4;
    const f32x4 bv = *(const f32x4*)(bias + mrow);
#pragma unroll
    for (int nf = 0; nf < 4; nf++) {
      const int p = p0 + w * 64 + nf * 16 + l15;
      float vr[4];
#pragma unroll
      for (int r = 0; r < 4; r++) {
        float v = acc[mf][nf][r] + bv[r];
        if (doRelu) v = fmaxf(v, 0.0f);
        vr[r] = v;
      }
      if (mode == 0) {
        unsigned long long pk = (unsigned long long)f2h(vr[0]) |
                                ((unsigned long long)f2h(vr[1]) << 16) |
                                ((unsigned long long)f2h(vr[2]) << 32) |
                                ((unsigned long long)f2h(vr[3]) << 48);
        *(unsigned long long*)(outT + ((size_t)b * 4096 + p) * M + mrow) = pk;
      } else {
#pragma unroll
        for (int r = 0; r < 4; r++)
          outN[((size_t)(b * M + mrow + r)) * 4096 + p] = f2h(vr[r]);
      }
    }
  }
}

// ---------------- fused QKV gemm: M=768 stacked weights, routed epilogue ----
__global__ __launch_bounds__(256) void gemm_qkv(
    const unsigned short* __restrict__ W768,  // fp16 [768][256] (wq|wk|wv)
    const float* __restrict__ bq, const float* __restrict__ bk,
    const float* __restrict__ bv_, const unsigned short* __restrict__ Xt,
    unsigned short* __restrict__ qT, unsigned short* __restrict__ kTo,
    unsigned short* __restrict__ vN) {
  __shared__ int4 WsL[64 * 32];
  __shared__ int4 XsL[128 * 8];
  const int b  = blockIdx.x;
  const int p0 = blockIdx.y * 256;
  const int z  = blockIdx.z;
  const int sel = z >> 2;
  const int m0 = (z & 3) * 64;
  const float* bias = (sel == 0) ? bq : (sel == 1) ? bk : bv_;
  const int tid = threadIdx.x;
  const int w = tid >> 6, l = tid & 63;
  const int l4 = l >> 4, l15 = l & 15;
  const int4* Wh4 = (const int4*)W768 + (size_t)sel * 256 * 32;
  const int4* Xt4 = (const int4*)Xt + (size_t)(b * 4096 + p0) * 32;
  for (int id = tid; id < 64 * 32; id += 256) {
    int row = id >> 5, g = id & 31;
    WsL[row * 32 + (g ^ (row & 7))] = Wh4[(size_t)(m0 + row) * 32 + g];
  }
  f32x4 acc[4][4];
#pragma unroll
  for (int i = 0; i < 4; i++)
#pragma unroll
    for (int j = 0; j < 4; j++) acc[i][j] = {0.f, 0.f, 0.f, 0.f};
  for (int cc = 0; cc < 8; cc++) {
    __syncthreads();
#pragma unroll
    for (int it = 0; it < 4; it++) {
      int id = tid + it * 256;
      int p = id >> 2, ch = id & 3;
      XsL[(p >> 1) * 8 + ((((p & 1) << 2) + ch) ^ ((p >> 1) & 7))] =
          Xt4[(size_t)p * 32 + cc * 4 + ch];
    }
    __syncthreads();
    half8 a[4], bx[4];
#pragma unroll
    for (int mf = 0; mf < 4; mf++) {
      int m = mf * 16 + l15;
      a[mf] = ((const half8*)WsL)[m * 32 + ((cc * 4 + l4) ^ (m & 7))];
    }
#pragma unroll
    for (int nf = 0; nf < 4; nf++) {
      int p = w * 64 + nf * 16 + l15;
      bx[nf] = ((const half8*)XsL)[(p >> 1) * 8 + ((((p & 1) << 2) + l4) ^ ((p >> 1) & 7))];
    }
#pragma unroll
    for (int mf = 0; mf < 4; mf++)
#pragma unroll
      for (int nf = 0; nf < 4; nf++)
        acc[mf][nf] = __builtin_amdgcn_mfma_f32_16x16x32_f16(a[mf], bx[nf], acc[mf][nf], 0, 0, 0);
  }
  unsigned short* outT = (sel == 0) ? qT : kTo;
#pragma unroll
  for (int mf = 0; mf < 4; mf++) {
    const int mrow = m0 + mf * 16 + l4 * 4;
    const f32x4 bvv = *(const f32x4*)(bias + mrow);
#pragma unroll
    for (int nf = 0; nf < 4; nf++) {
      const int p = p0 + w * 64 + nf * 16 + l15;
      float vr[4];
#pragma unroll
      for (int r = 0; r < 4; r++) vr[r] = acc[mf][nf][r] + bvv[r];
      if (sel < 2) {
        unsigned long long pk = (unsigned long long)f2h(vr[0]) |
                                ((unsigned long long)f2h(vr[1]) << 16) |
                                ((unsigned long long)f2h(vr[2]) << 32) |
                                ((unsigned long long)f2h(vr[3]) << 48);
        *(unsigned long long*)(outT + ((size_t)b * 4096 + p) * 256 + mrow) = pk;
      } else {
#pragma unroll
        for (int r = 0; r < 4; r++)
          vN[((size_t)(b * 256 + mrow + r)) * 4096 + p] = f2h(vr[r]);
      }
    }
  }
}

// ---------------- 3x3 conv, fp16 MFMA implicit GEMM ------------------------
__global__ __launch_bounds__(256, 2) void conv3x3_mfma(
    const unsigned short* __restrict__ inT,
    const unsigned short* __restrict__ wA,
    const float* __restrict__ bias,
    unsigned short* __restrict__ outT,
    float* __restrict__ outN,
    int mode) {
  __shared__ int4 wS[2304];
  __shared__ int4 inS[1584];
  const int b  = blockIdx.x;
  const int y0 = blockIdx.y * 4;
  const int o0 = blockIdx.z * 64;
  const int tid = threadIdx.x;
  const int w = tid >> 6, l = tid & 63;
  const int l4 = l >> 4, l15 = l & 15;
  const int4* inT4 = (const int4*)inT + (size_t)b * 4096 * 32;
  const int4* wA4  = (const int4*)wA;
  f32x4 acc[4][4];
#pragma unroll
  for (int i = 0; i < 4; i++)
#pragma unroll
    for (int j = 0; j < 4; j++) acc[i][j] = {0.f, 0.f, 0.f, 0.f};

  for (int c0 = 0; c0 < 256; c0 += 32) {
    __syncthreads();
#pragma unroll
    for (int it = 0; it < 9; it++) {
      int id = it * 256 + tid;
      int ch = id & 3;
      int r  = id >> 2;
      int tap = r % 9, ol = r / 9;
      int sbw = tap * 32 + (ol >> 1);
      int slot = (4 * (ol & 1) + ch) ^ (sbw & 7);
      wS[sbw * 8 + slot] = wA4[((size_t)(o0 + ol) * 9 + tap) * 32 + (c0 >> 3) + ch];
    }
#pragma unroll
    for (int it = 0; it < 6; it++) {
      int ch = tid & 3;
      int col = tid >> 2;
      int yimg = y0 + it - 1;
      int4 v = {0, 0, 0, 0};
      if (yimg >= 0 && yimg < 64)
        v = inT4[(size_t)(yimg * 64 + col) * 32 + (c0 >> 3) + ch];
      int cl = col + 1;
      int sb = it * 33 + (cl >> 1);
      int slot = (4 * (cl & 1) + ch) ^ (sb & 7);
      inS[sb * 8 + slot] = v;
    }
    if (tid < 48) {
      int row = tid >> 3;
      int cl = ((tid >> 2) & 1) ? 65 : 0;
      int ch = tid & 3;
      int sb = row * 33 + (cl >> 1);
      int slot = (4 * (cl & 1) + ch) ^ (sb & 7);
      inS[sb * 8 + slot] = {0, 0, 0, 0};
    }
    __syncthreads();
#pragma unroll
    for (int tap = 0; tap < 9; tap++) {
      const int dy = tap / 3, dx = tap % 3;
      half8 a[4], bf[4];
#pragma unroll
      for (int mf = 0; mf < 4; mf++) {
        int oc = mf * 16 + l15;
        int sbw = tap * 32 + (oc >> 1);
        a[mf] = ((const half8*)wS)[sbw * 8 + ((4 * (oc & 1) + l4) ^ (sbw & 7))];
      }
#pragma unroll
      for (int nf = 0; nf < 4; nf++) {
        int cl = nf * 16 + l15 + dx;
        int row = w + dy;
        int sb = row * 33 + (cl >> 1);
        bf[nf] = ((const half8*)inS)[sb * 8 + ((4 * (cl & 1) + l4) ^ (sb & 7))];
      }
#pragma unroll
      for (int mf = 0; mf < 4; mf++)
#pragma unroll
        for (int nf = 0; nf < 4; nf++)
          acc[mf][nf] = __builtin_amdgcn_mfma_f32_16x16x32_f16(a[mf], bf[nf], acc[mf][nf], 0, 0, 0);
    }
  }
  const int p_base = (y0 + w) * 64;
#pragma unroll
  for (int mf = 0; mf < 4; mf++) {
    const int ocb = o0 + mf * 16 + l4 * 4;
    const f32x4 bv = *(const f32x4*)(bias + ocb);
#pragma unroll
    for (int nf = 0; nf < 4; nf++) {
      const int p = p_base + nf * 16 + l15;
      if (mode == 0) {
        unsigned short h[4];
#pragma unroll
        for (int r = 0; r < 4; r++)
          h[r] = f2h(fmaxf(acc[mf][nf][r] + bv[r], 0.0f));
        unsigned long long pk = (unsigned long long)h[0] |
                                ((unsigned long long)h[1] << 16) |
                                ((unsigned long long)h[2] << 32) |
                                ((unsigned long long)h[3] << 48);
        *(unsigned long long*)(outT + ((size_t)b * 4096 + p) * 256 + ocb) = pk;
      } else {
#pragma unroll
        for (int r = 0; r < 4; r++)
          outN[((size_t)(b * 256 + ocb + r)) * HW + p] = acc[mf][nf][r] + bv[r];
      }
    }
  }
}

// ---------------- attention pass 1a: t-sliced waves, K fully in regs --------
__global__ __launch_bounds__(256) void attn_rowstats_part(
    const unsigned short* __restrict__ kT, const unsigned short* __restrict__ qT,
    float* __restrict__ Mp, float* __restrict__ Zp) {
  __shared__ int4 qs4[64][32];   // 32KB [t][c-granule], swizzled
  const int b  = blockIdx.x;
  const int r0 = blockIdx.y * 64;
  const int q  = blockIdx.z;
  const int tid = threadIdx.x;
  const int w = tid >> 6, l = tid & 63;
  const int l4 = l >> 4, l15 = l & 15;
  const int4* qT4 = (const int4*)qT + (size_t)b * HW * 32;
  const half8* kT8 = (const half8*)kT + ((size_t)b * HW + r0) * 32;
  half8 afr[4][8];               // all 64 rows: [mfl][g]
#pragma unroll
  for (int mfl = 0; mfl < 4; mfl++)
#pragma unroll
    for (int g = 0; g < 8; g++)
      afr[mfl][g] = kT8[(size_t)(mfl * 16 + l15) * 32 + g * 4 + l4];
  float m[4][4], z[4][4];        // [mfl][reg]
#pragma unroll
  for (int i = 0; i < 4; i++)
#pragma unroll
    for (int j = 0; j < 4; j++) { m[i][j] = -1e30f; z[i][j] = 0.0f; }
  for (int t0 = q * 1024; t0 < q * 1024 + 1024; t0 += 64) {
    __syncthreads();
#pragma unroll
    for (int it = 0; it < 8; it++) {
      int id = tid + it * 256;
      int row = id >> 5, ch = id & 31;
      qs4[row][ch ^ (row & 7)] = qT4[(size_t)(t0 + row) * 32 + ch];
    }
    __syncthreads();
    f32x4 acc[4] = {{0.f,0.f,0.f,0.f},{0.f,0.f,0.f,0.f},
                    {0.f,0.f,0.f,0.f},{0.f,0.f,0.f,0.f}};
    const int t = w * 16 + l15;  // this wave's t-slice
#pragma unroll
    for (int g = 0; g < 8; g++) {
      half8 bq = ((const half8*)qs4)[t * 32 + ((g * 4 + l4) ^ (t & 7))];
#pragma unroll
      for (int mfl = 0; mfl < 4; mfl++)
        acc[mfl] = __builtin_amdgcn_mfma_f32_16x16x32_f16(afr[mfl][g], bq, acc[mfl], 0, 0, 0);
    }
#pragma unroll
    for (int mfl = 0; mfl < 4; mfl++)
#pragma unroll
      for (int r = 0; r < 4; r++) {
        float sv = acc[mfl][r];
        if (sv > m[mfl][r]) { z[mfl][r] *= __expf(m[mfl][r] - sv); m[mfl][r] = sv; }
        z[mfl][r] += __expf(sv - m[mfl][r]);
      }
  }
#pragma unroll
  for (int mfl = 0; mfl < 4; mfl++)
#pragma unroll
    for (int r = 0; r < 4; r++) {
      for (int off = 1; off < 16; off <<= 1) {
        float mo = __shfl_xor(m[mfl][r], off, 16);
        float zo = __shfl_xor(z[mfl][r], off, 16);
        float mn = fmaxf(m[mfl][r], mo);
        z[mfl][r] = z[mfl][r] * __expf(m[mfl][r] - mn) + zo * __expf(mo - mn);
        m[mfl][r] = mn;
      }
    }
  if (l15 == 0) {
#pragma unroll
    for (int mfl = 0; mfl < 4; mfl++)
#pragma unroll
      for (int r = 0; r < 4; r++) {
        int rr = r0 + mfl * 16 + l4 * 4 + r;
        Mp[((size_t)b * HW + rr) * 16 + q * 4 + w] = m[mfl][r];
        Zp[((size_t)b * HW + rr) * 16 + q * 4 + w] = z[mfl][r];
      }
  }
}

// ---------------- attention pass 1b: merge 16 partials ----------------------
__global__ __launch_bounds__(256) void reduce_mz(
    const float* __restrict__ Mp, const float* __restrict__ Zp,
    float* __restrict__ Mrow, float* __restrict__ Zrow) {
  int i = blockIdx.x * 256 + threadIdx.x;      // 0 .. 8*4096-1
  float mq[16], zq[16];
#pragma unroll
  for (int j = 0; j < 4; j++) {
    float4 mv = *(const float4*)(Mp + (size_t)i * 16 + j * 4);
    float4 zv = *(const float4*)(Zp + (size_t)i * 16 + j * 4);
    mq[j*4+0] = mv.x; mq[j*4+1] = mv.y; mq[j*4+2] = mv.z; mq[j*4+3] = mv.w;
    zq[j*4+0] = zv.x; zq[j*4+1] = zv.y; zq[j*4+2] = zv.z; zq[j*4+3] = zv.w;
  }
  float M = mq[0];
#pragma unroll
  for (int j = 1; j < 16; j++) M = fmaxf(M, mq[j]);
  float Z = 0.0f;
#pragma unroll
  for (int j = 0; j < 16; j++) Z += zq[j] * __expf(mq[j] - M);
  Mrow[i] = M;
  Zrow[i] = 1.0f / Z;
}

// ---------------- attention pass 2 (R6-exact): bp-once + early V preload ----
__global__ __launch_bounds__(256, 2) void attn_pass2(
    const unsigned short* __restrict__ kT, const unsigned short* __restrict__ qT,
    const unsigned short* __restrict__ vB, const float* __restrict__ Mrow,
    const float* __restrict__ Zrow, const float* __restrict__ alphap,
    const float* __restrict__ betap, float* __restrict__ out) {
  __shared__ int4 qs4[64][32];      // 32KB Q [t][c-granule], swizzled
  __shared__ int4 ps4[2][64][16];   // 2x16KB P [t][r-granule], swizzled
  const int b  = blockIdx.x;
  const int t0 = blockIdx.y * 64;
  const int tid = threadIdx.x;
  const int w = tid >> 6, l = tid & 63;
  const int l4 = l >> 4, l15 = l & 15;
  const int4*  qT4 = (const int4*)qT + ((size_t)b * HW + t0) * 32;
  const half8* kT8 = (const half8*)kT + (size_t)b * HW * 32;
  const half8* vB8 = (const half8*)vB + (size_t)b * 256 * 512;
  const float* Mb = Mrow + (size_t)b * HW;
  const float* Zb = Zrow + (size_t)b * HW;
#pragma unroll
  for (int it = 0; it < 8; it++) {
    int id = tid + it * 256;
    int row = id >> 5, ch = id & 31;
    qs4[row][ch ^ (row & 7)] = qT4[(size_t)row * 32 + ch];
  }
  f32x4 acc_o[4][4];
#pragma unroll
  for (int i = 0; i < 4; i++)
#pragma unroll
    for (int j = 0; j < 4; j++) acc_o[i][j] = {0.f, 0.f, 0.f, 0.f};
  __syncthreads();

#pragma unroll 1
  for (int iter = 0; iter < 32; iter++) {
    const int r0 = iter * 128;
    int4* psb = &ps4[iter & 1][0][0];
    half8 ak0[8], ak1[8];
#pragma unroll
    for (int g = 0; g < 8; g++) {
      ak0[g] = kT8[(size_t)(r0 + w * 32 + l15) * 32 + g * 4 + l4];
      ak1[g] = kT8[(size_t)(r0 + w * 32 + 16 + l15) * 32 + g * 4 + l4];
    }
    f32x4 acc_s[2][4];
#pragma unroll
    for (int i = 0; i < 2; i++)
#pragma unroll
      for (int j = 0; j < 4; j++) acc_s[i][j] = {0.f, 0.f, 0.f, 0.f};
#pragma unroll
    for (int g = 0; g < 8; g++) {
      half8 bq[4];
#pragma unroll
      for (int nf = 0; nf < 4; nf++) {
        int t = nf * 16 + l15;
        bq[nf] = ((const half8*)qs4)[t * 32 + ((g * 4 + l4) ^ (t & 7))];
      }
#pragma unroll
      for (int nf = 0; nf < 4; nf++) {
        acc_s[0][nf] = __builtin_amdgcn_mfma_f32_16x16x32_f16(ak0[g], bq[nf], acc_s[0][nf], 0, 0, 0);
        acc_s[1][nf] = __builtin_amdgcn_mfma_f32_16x16x32_f16(ak1[g], bq[nf], acc_s[1][nf], 0, 0, 0);
      }
    }
    half8 avr[4][4];   // [cc4][ks]
#pragma unroll
    for (int cc4 = 0; cc4 < 2; cc4++) {
      const int c = cc4 * 64 + w * 16 + l15;
#pragma unroll
      for (int ks = 0; ks < 4; ks++)
        avr[cc4][ks] = vB8[(size_t)c * 512 + (r0 >> 3) + ks * 4 + l4];
    }
#pragma unroll
    for (int mfl = 0; mfl < 2; mfl++) {
      int rbase = r0 + w * 32 + mfl * 16 + l4 * 4;
      f32x4 Mv = *(const f32x4*)(Mb + rbase);
      f32x4 Zv = *(const f32x4*)(Zb + rbase);
      int slot = w * 8 + mfl * 4 + l4;
#pragma unroll
      for (int nf = 0; nf < 4; nf++) {
        int t = nf * 16 + l15;
        unsigned lo = (unsigned)f2h(__expf(acc_s[mfl][nf][0] - Mv[0]) * Zv[0])
                    | ((unsigned)f2h(__expf(acc_s[mfl][nf][1] - Mv[1]) * Zv[1]) << 16);
        unsigned hi = (unsigned)f2h(__expf(acc_s[mfl][nf][2] - Mv[2]) * Zv[2])
                    | ((unsigned)f2h(__expf(acc_s[mfl][nf][3] - Mv[3]) * Zv[3]) << 16);
        int ch = slot >> 1;
        int fslot = ((ch ^ (t & 7)) << 1) | (slot & 1);
        ((unsigned long long*)psb)[(size_t)t * 32 + fslot] =
            ((unsigned long long)hi << 32) | (unsigned long long)lo;
      }
    }
    __syncthreads();
#pragma unroll
    for (int cc4 = 2; cc4 < 4; cc4++) {
      const int c = cc4 * 64 + w * 16 + l15;
#pragma unroll
      for (int ks = 0; ks < 4; ks++)
        avr[cc4][ks] = vB8[(size_t)c * 512 + (r0 >> 3) + ks * 4 + l4];
    }
#pragma unroll
    for (int ks = 0; ks < 4; ks++) {
#pragma unroll
      for (int nf = 0; nf < 4; nf++) {
        int t = nf * 16 + l15;
        half8 bp = ((const half8*)psb)[t * 16 + ((ks * 4 + l4) ^ (t & 7))];
#pragma unroll
        for (int cc4 = 0; cc4 < 4; cc4++)
          acc_o[cc4][nf] = __builtin_amdgcn_mfma_f32_16x16x32_f16(avr[cc4][ks], bp, acc_o[cc4][nf], 0, 0, 0);
      }
    }
  }
  const float alpha = alphap[0], beta = betap[0];
#pragma unroll
  for (int cc4 = 0; cc4 < 4; cc4++) {
    int cbase = cc4 * 64 + w * 16 + l4 * 4;
#pragma unroll
    for (int nf = 0; nf < 4; nf++) {
      int t = t0 + nf * 16 + l15;
#pragma unroll
      for (int r = 0; r < 4; r++) {
        size_t idx = ((size_t)(b * 256 + cbase + r)) * HW + t;
        out[idx] = alpha * out[idx] + beta * acc_o[cc4][nf][r];
      }
    }
  }
}

extern "C" void kernel_launch(void* const* d_in, const int* in_sizes, int n_in,
                              void* d_out, int out_size, void* d_ws, size_t ws_size,
                              hipStream_t stream) {
  (void)in_sizes; (void)n_in; (void)out_size; (void)ws_size;
  const float* x   = (const float*)d_in[0];
  const float* w1  = (const float*)d_in[1];
  const float* b1  = (const float*)d_in[2];
  const float* w2  = (const float*)d_in[3];
  const float* b2  = (const float*)d_in[4];
  const float* w3  = (const float*)d_in[5];
  const float* b3  = (const float*)d_in[6];
  const float* wb1 = (const float*)d_in[7];
  const float* bb1 = (const float*)d_in[8];
  const float* wb2 = (const float*)d_in[9];
  const float* bb2 = (const float*)d_in[10];
  const float* wq  = (const float*)d_in[11];
  const float* bq  = (const float*)d_in[12];
  const float* wk  = (const float*)d_in[13];
  const float* bk  = (const float*)d_in[14];
  const float* wv  = (const float*)d_in[15];
  const float* bv  = (const float*)d_in[16];
  const float* alpha = (const float*)d_in[17];
  const float* beta  = (const float*)d_in[18];
  float* out = (float*)d_out;

  const size_t SZH = (size_t)NB * 4096 * 256;   // 8,388,608 halves = 16MB
  unsigned short* wsh = (unsigned short*)d_ws;
  unsigned short* xh  = wsh;
  unsigned short* xfT = wsh + SZH;
  unsigned short* qT  = wsh + 2 * SZH;
  unsigned short* kT  = wsh + 3 * SZH;
  unsigned short* vN  = wsh + 4 * SZH;
  unsigned short* y1T = wsh + 5 * SZH;
  unsigned short* y2T = y1T + SZH / 4;
  unsigned short* t1T = wsh + 5 * SZH;
  float* Mrow = (float*)(wsh + 6 * SZH);
  float* Zrow = Mrow + (size_t)NB * HW;
  float* Mp   = Zrow + (size_t)NB * HW;         // [B*HW*16] partials
  float* Zp   = Mp + (size_t)NB * HW * 16;
  unsigned short* wh   = (unsigned short*)(Zp + (size_t)NB * HW * 16);
  unsigned short* w1h  = wh;
  unsigned short* w2h  = wh + 16384;
  unsigned short* w3h  = wh + 24576;
  unsigned short* wqh  = wh + 57344;            // [768][256] contiguous q|k|v
  unsigned short* wA1h = wh + 253952;
  unsigned short* wA2h = wA1h + (size_t)256 * 9 * 256;

  wcvt6<<<992, 256, 0, stream>>>(w1, w2, w3, wq, wk, wv, wh);
  wreorder<<<256, 256, 0, stream>>>(wb1, wA1h);
  wreorder<<<256, 256, 0, stream>>>(wb2, wA2h);
  transpose_cvt_h<<<dim3(8, 64, 4), 256, 0, stream>>>(x, xh);
  gemm1x1_h<<<dim3(8, 16, 1), 256, 0, stream>>>(w1h, b1, xh,  y1T, nullptr, 256,  64, 0, 1);
  gemm1x1_h<<<dim3(8, 16, 2), 256, 0, stream>>>(w2h, b2, y1T, y2T, nullptr,  64, 128, 0, 1);
  gemm1x1_h<<<dim3(8, 16, 4), 256, 0, stream>>>(w3h, b3, y2T, xfT, nullptr, 128, 256, 0, 1);
  gemm_qkv<<<dim3(8, 16, 12), 256, 0, stream>>>(wqh, bq, bk, bv, xfT, qT, kT, vN);
  conv3x3_mfma<<<dim3(8, 16, 4), 256, 0, stream>>>(xfT, wA1h, bb1, t1T, nullptr, 0);
  conv3x3_mfma<<<dim3(8, 16, 4), 256, 0, stream>>>(t1T, wA2h, bb2, nullptr, out, 1);
  attn_rowstats_part<<<dim3(8, 64, 4), 256, 0, stream>>>(kT, qT, Mp, Zp);
  reduce_mz<<<128, 256, 0, stream>>>(Mp, Zp, Mrow, Zrow);
  attn_pass2<<<dim3(8, 64), 256, 0, stream>>>(kT, qT, vN, Mrow, Zrow,
                                              alpha, beta, out);
}